// Round 1
// 200.271 us; speedup vs baseline: 1.0302x; 1.0302x over previous
//
#include <hip/hip_runtime.h>
#include <hip/hip_bf16.h>

#define T_SEQ 4096
#define C_EMB 768
#define HEAD  64

typedef short  short4v __attribute__((ext_vector_type(4)));
typedef short  short8  __attribute__((ext_vector_type(8)));
typedef float  floatx4 __attribute__((ext_vector_type(4)));
typedef unsigned int uint2v __attribute__((ext_vector_type(2)));

static __device__ __forceinline__ short f2bf(float v) {
    __hip_bfloat16 h = __float2bfloat16(v);
    return *reinterpret_cast<short*>(&h);
}

// ---------------------------------------------------------------------------
// Kernel 0: transpose+downcast fp32 W[768][64] -> bf16 Wt[g][n=64][k=768]
// Reads COALESCED over input layout (n fastest), writes scattered (stores
// are fire-and-forget; the old version gathered 256B-stride reads).
// ---------------------------------------------------------------------------
__global__ void wt_transpose_kernel(const float* __restrict__ Wk,
                                    const float* __restrict__ Wq,
                                    const float* __restrict__ Wv,
                                    short* __restrict__ Wt) {
    const int per = HEAD * C_EMB;
    const int total = 3 * per;
    for (int idx = blockIdx.x * blockDim.x + threadIdx.x; idx < total;
         idx += gridDim.x * blockDim.x) {
        int g   = idx / per;
        int rem = idx - g * per;     // rem = k*HEAD + n  (input-linear)
        int k   = rem >> 6;          // HEAD = 64
        int n   = rem & 63;
        const float* W = (g == 0) ? Wk : (g == 1) ? Wq : Wv;
        Wt[((size_t)(g * HEAD + n)) * C_EMB + k] = f2bf(W[rem]);
    }
}

// ---------------------------------------------------------------------------
// Kernel 1: QKV via MFMA. 1024 blocks x 256 thr (4 waves): each wave owns
// 3 of the 12 (K|Q|V) column-frags over full K=768 -> 4096 waves (16/CU,
// 4/SIMD) instead of the old 1024 (1/SIMD, latency-exposed W loads).
// x rows shared by the 4 waves via L1/L2; HBM still reads x once.
// K stored PRESCALED by 768^-0.5*log2(e).
// ---------------------------------------------------------------------------
__global__ __launch_bounds__(256) void qkv_mfma(
    const float* __restrict__ x, const short* __restrict__ Wt,
    const float* __restrict__ bkp, const float* __restrict__ bqp,
    const float* __restrict__ bvp,
    short* __restrict__ Kb, short* __restrict__ Qb, short* __restrict__ Vt) {
    const float scale2 = 0.052058773f;   // 768^-0.5 * log2(e)
    int lane = threadIdx.x & 63;
    int wid  = threadIdx.x >> 6;         // 0..3 -> j = wid*3 .. wid*3+2
    int ln15 = lane & 15, quad = lane >> 4;
    int rowblk = blockIdx.x;             // 0..1023: 16-row group
    const float* xrow = x + (size_t)(rowblk * 16 + ln15) * C_EMB + quad * 8;

    const short* wp[3];
#pragma unroll
    for (int j0 = 0; j0 < 3; ++j0) {
        int j = wid * 3 + j0;
        int g = j >> 2, nl = (j & 3) * 16 + ln15;
        wp[j0] = Wt + ((size_t)(g * HEAD + nl)) * C_EMB + quad * 8;
    }

    // 4-deep rotating x prefetch buffer
    floatx4 xb[4][2];
#pragma unroll
    for (int i = 0; i < 4; ++i) {
        xb[i][0] = *(const floatx4*)(xrow + i * 32);
        xb[i][1] = *(const floatx4*)(xrow + i * 32 + 4);
    }

    floatx4 acc[3];
#pragma unroll
    for (int j0 = 0; j0 < 3; ++j0) acc[j0] = (floatx4){0.f, 0.f, 0.f, 0.f};

#pragma unroll
    for (int kc = 0; kc < 24; ++kc) {
        short8 a;
#pragma unroll
        for (int e = 0; e < 4; ++e) {
            a[e]     = f2bf(xb[kc & 3][0][e]);
            a[4 + e] = f2bf(xb[kc & 3][1][e]);
        }
        int nk = (kc + 4 < 24) ? kc + 4 : 23;   // clamped depth-4 prefetch
        xb[kc & 3][0] = *(const floatx4*)(xrow + nk * 32);
        xb[kc & 3][1] = *(const floatx4*)(xrow + nk * 32 + 4);
        short8 wf[3];
#pragma unroll
        for (int j0 = 0; j0 < 3; ++j0) wf[j0] = *(const short8*)(wp[j0] + kc * 32);
#pragma unroll
        for (int j0 = 0; j0 < 3; ++j0)
            acc[j0] = __builtin_amdgcn_mfma_f32_16x16x32_bf16(a, wf[j0], acc[j0], 0, 0, 0);
    }

#pragma unroll
    for (int j0 = 0; j0 < 3; ++j0) {
        int j  = wid * 3 + j0;
        int g  = j >> 2;
        int nl = (j & 3) * 16 + ln15;
        float bias = (g == 0 ? bkp : g == 1 ? bqp : bvp)[nl];
#pragma unroll
        for (int r = 0; r < 4; ++r) {
            int grow = rowblk * 16 + quad * 4 + r;   // C/D row
            float v = acc[j0][r] + bias;
            if (g == 0)      Kb[(size_t)grow * HEAD + nl] = f2bf(v * scale2);
            else if (g == 1) Qb[(size_t)grow * HEAD + nl] = f2bf(v);
            else {
                int b = grow >> 12, t = grow & 4095;
                Vt[((size_t)(b * HEAD + nl) << 12) + t] = f2bf(v);  // V transposed
            }
        }
    }
}

// ---------------------------------------------------------------------------
// Kernel 2: causal attention partial. One wave/block, 32 t-rows/wave,
// s-chunks of FOUR tiles (was 16): grid (128 g32, 16 chunks, 4 batches)
// -> 4352 useful waves (~17/CU, 4.25/SIMD; was 1280 -> 2.5/CU) so VALU/
// transcendental and load latency overlap across waves, and the longest
// wave shrinks 16 -> 4 tile-iters. exp via raw v_exp_f32 (inputs |x|<~2:
// scale folded into K), P->bf16 via v_cvt_pk_bf16_f32 (1 inst / 2 vals).
// S computed transposed (A=Q, B=K loop-invariant); fp32 atomicAdd merge.
// ---------------------------------------------------------------------------
__global__ __launch_bounds__(64) void attn_part(
    const short* __restrict__ Kb, const short* __restrict__ Qb,
    const short* __restrict__ Vt, float* __restrict__ Oacc,
    float* __restrict__ lacc) {
    __shared__ __align__(16) short Ps[32][72];   // [t_loc][s_loc] wave-local

    int lane = threadIdx.x & 63;
    int ln15 = lane & 15, quad = lane >> 4;
    int g32 = blockIdx.x, c = blockIdx.y, b = blockIdx.z;
    int dtile = g32 >> 1;                 // diagonal s-tile (uniform per 32-tile)
    int lo = c * 4;
    if (lo > dtile) return;
    int hi = min(dtile, lo + 3);
    int base = g32 * 32;

    // K B-frags (prescaled), loop-invariant: B[k=h][n=t]
    short8 bk[2][2];
#pragma unroll
    for (int tg = 0; tg < 2; ++tg) {
        const short* kp = Kb + ((size_t)(b * T_SEQ + base + tg * 16 + ln15)) * HEAD + quad * 8;
        bk[tg][0] = *(const short8*)kp;
        bk[tg][1] = *(const short8*)(kp + 32);
    }

    floatx4 o[2][4];
#pragma unroll
    for (int tg = 0; tg < 2; ++tg)
#pragma unroll
        for (int hb = 0; hb < 4; ++hb) o[tg][hb] = (floatx4){0.f, 0.f, 0.f, 0.f};
    float ls[2] = {0.f, 0.f};

    const short* qp = Qb + ((size_t)(b * T_SEQ + lo * 64 + ln15)) * HEAD + quad * 8;
    const short* vp = Vt + (((size_t)(b * HEAD + ln15)) << 12) + lo * 64 + quad * 8;

    for (int st = lo; st <= hi; ++st) {
        // ALL loads upfront: 8 Q frags + 8 V frags (16 KB/wave in flight)
        short8 aq[4][2], bv[4][2];
#pragma unroll
        for (int sb = 0; sb < 4; ++sb) {
            aq[sb][0] = *(const short8*)(qp + sb * 16 * HEAD);
            aq[sb][1] = *(const short8*)(qp + sb * 16 * HEAD + 32);
        }
#pragma unroll
        for (int hb = 0; hb < 4; ++hb) {
            bv[hb][0] = *(const short8*)(vp + ((size_t)hb << 16));
            bv[hb][1] = *(const short8*)(vp + ((size_t)hb << 16) + 32);
        }

        // S^T = Q . K^T : D row = s_loc = sb*16+quad*4+r, col = t_loc = ln15
        floatx4 sacc[4][2];
#pragma unroll
        for (int sb = 0; sb < 4; ++sb)
#pragma unroll
            for (int tg = 0; tg < 2; ++tg) {
                floatx4 z = (floatx4){0.f, 0.f, 0.f, 0.f};
                z = __builtin_amdgcn_mfma_f32_16x16x32_bf16(aq[sb][0], bk[tg][0], z, 0, 0, 0);
                z = __builtin_amdgcn_mfma_f32_16x16x32_bf16(aq[sb][1], bk[tg][1], z, 0, 0, 0);
                sacc[sb][tg] = z;
            }

        // p = exp2(z) (bounded; scale folded into K); mask diag; pack P
        bool diag = (st == dtile);
        int s0 = st * 64;
#pragma unroll
        for (int tg = 0; tg < 2; ++tg) {
            int tgl = base + tg * 16 + ln15;
#pragma unroll
            for (int sb = 0; sb < 4; ++sb) {
                float pv[4];
#pragma unroll
                for (int r = 0; r < 4; ++r) {
                    float p = __builtin_amdgcn_exp2f(sacc[sb][tg][r]);
                    if (diag) {
                        int sg = s0 + sb * 16 + quad * 4 + r;
                        p = (sg > tgl) ? 0.f : p;
                    }
                    pv[r] = p;
                }
                ls[tg] += (pv[0] + pv[1]) + (pv[2] + pv[3]);
                unsigned a01, a23;
                asm("v_cvt_pk_bf16_f32 %0, %1, %2" : "=v"(a01) : "v"(pv[0]), "v"(pv[1]));
                asm("v_cvt_pk_bf16_f32 %0, %1, %2" : "=v"(a23) : "v"(pv[2]), "v"(pv[3]));
                *(uint2v*)&Ps[tg * 16 + ln15][sb * 16 + quad * 4] = (uint2v){a01, a23};
            }
        }
        __asm__ volatile("s_waitcnt lgkmcnt(0)" ::: "memory");
        short8 ap[2][2];
#pragma unroll
        for (int tg = 0; tg < 2; ++tg) {
            ap[tg][0] = *(const short8*)&Ps[tg * 16 + ln15][quad * 8];
            ap[tg][1] = *(const short8*)&Ps[tg * 16 + ln15][32 + quad * 8];
        }

        // O += P . V
#pragma unroll
        for (int tg = 0; tg < 2; ++tg)
#pragma unroll
            for (int hb = 0; hb < 4; ++hb) {
                o[tg][hb] = __builtin_amdgcn_mfma_f32_16x16x32_bf16(ap[tg][0], bv[hb][0], o[tg][hb], 0, 0, 0);
                o[tg][hb] = __builtin_amdgcn_mfma_f32_16x16x32_bf16(ap[tg][1], bv[hb][1], o[tg][hb], 0, 0, 0);
            }

        qp += 64 * HEAD;
        vp += 64;
    }

    // l partial: reduce over quads (lane ln15 holds t = base+tg*16+ln15)
#pragma unroll
    for (int tg = 0; tg < 2; ++tg) {
        float v = ls[tg];
        v += __shfl_xor(v, 16, 64);
        v += __shfl_xor(v, 32, 64);
        if (quad == 0)
            atomicAdd(lacc + (size_t)b * T_SEQ + base + tg * 16 + ln15, v);
    }
#pragma unroll
    for (int tg = 0; tg < 2; ++tg)
#pragma unroll
        for (int r = 0; r < 4; ++r) {
            int t = base + tg * 16 + quad * 4 + r;
#pragma unroll
            for (int hb = 0; hb < 4; ++hb)
                atomicAdd(Oacc + ((size_t)(b * T_SEQ + t)) * HEAD + hb * 16 + ln15,
                          o[tg][hb][r]);
        }
}

// ---------------------------------------------------------------------------
// Kernel 3: out = Oacc / lacc (fp32)
// ---------------------------------------------------------------------------
__global__ __launch_bounds__(256) void attn_div(
    const float* __restrict__ Oacc, const float* __restrict__ lacc,
    float* __restrict__ out) {
    int idx = blockIdx.x * 256 + threadIdx.x;   // 0 .. 1048575
    out[idx] = Oacc[idx] / lacc[idx >> 6];
}

extern "C" void kernel_launch(void* const* d_in, const int* in_sizes, int n_in,
                              void* d_out, int out_size, void* d_ws, size_t ws_size,
                              hipStream_t stream) {
    // Size-based input mapping (order-robust; W's and b's keep internal order)
    const int XSZ = 4 * T_SEQ * C_EMB;   // 12582912
    const int WSZ = C_EMB * HEAD;        // 49152
    const int BSZ = HEAD;                // 64
    const float* x = nullptr;
    const float* W[3] = {nullptr, nullptr, nullptr};
    const float* B[3] = {nullptr, nullptr, nullptr};
    int iw = 0, ib = 0;
    for (int i = 0; i < n_in; ++i) {
        if (in_sizes[i] == XSZ) x = (const float*)d_in[i];
        else if (in_sizes[i] == WSZ && iw < 3) W[iw++] = (const float*)d_in[i];
        else if (in_sizes[i] == BSZ && ib < 3) B[ib++] = (const float*)d_in[i];
    }

    short* ws = (short*)d_ws;
    short* Kb = ws;                               // [16384][64] bf16   2 MB
    short* Qb = Kb + (size_t)4 * T_SEQ * HEAD;    // [16384][64] bf16   2 MB
    short* Vt = Qb + (size_t)4 * T_SEQ * HEAD;    // [4][64][4096] bf16 2 MB
    short* Wt = Vt + (size_t)4 * HEAD * T_SEQ;    // [3][64][768] bf16  288 KB
    float* Oacc = (float*)(Wt + (size_t)3 * HEAD * C_EMB); // [4][4096][64] 4 MB
    float* lacc = Oacc + (size_t)4 * T_SEQ * HEAD;         // [4][4096] 64 KB

    hipMemsetAsync(Oacc, 0,
                   ((size_t)4 * T_SEQ * HEAD + 4 * T_SEQ) * sizeof(float),
                   stream);
    wt_transpose_kernel<<<96, 256, 0, stream>>>(W[0], W[1], W[2], Wt);
    qkv_mfma<<<1024, 256, 0, stream>>>(x, Wt, B[0], B[1], B[2], Kb, Qb, Vt);
    attn_part<<<dim3(128, 16, 4), 64, 0, stream>>>(Kb, Qb, Vt, Oacc, lacc);
    attn_div<<<4096, 256, 0, stream>>>(Oacc, lacc, (float*)d_out);
}

// Round 2
// 171.219 us; speedup vs baseline: 1.2049x; 1.1697x over previous
//
#include <hip/hip_runtime.h>
#include <hip/hip_bf16.h>

#define T_SEQ 4096
#define C_EMB 768
#define HEAD  64

typedef short  short4v __attribute__((ext_vector_type(4)));
typedef short  short8  __attribute__((ext_vector_type(8)));
typedef float  floatx4 __attribute__((ext_vector_type(4)));
typedef unsigned int uint2v __attribute__((ext_vector_type(2)));

static __device__ __forceinline__ short f2bf(float v) {
    __hip_bfloat16 h = __float2bfloat16(v);
    return *reinterpret_cast<short*>(&h);
}

// ---------------------------------------------------------------------------
// Kernel 0: fp32 W[768][64] (x3) -> bf16 Wf in MFMA-FRAGMENT order:
//   Wf[((j*24 + kc)*64 + lane)*8 + e] = bf16(W_g[k][n])
//   g = j>>2, n = (j&3)*16 + (lane&15), k = kc*32 + (lane>>4)*8 + e
// so a wave's (j,kc) fragment load in kernel 1 is 64 lanes x 16 B CONTIGUOUS
// (the old column-major layout made every W load 64 scattered 1536B-stride
// requests -> TA request-rate bound).
// ---------------------------------------------------------------------------
__global__ void wt_transpose_kernel(const float* __restrict__ Wk,
                                    const float* __restrict__ Wq,
                                    const float* __restrict__ Wv,
                                    short* __restrict__ Wf) {
    const int total = 12 * 24 * 64 * 8;   // 147456
    for (int idx = blockIdx.x * blockDim.x + threadIdx.x; idx < total;
         idx += gridDim.x * blockDim.x) {
        int e    = idx & 7;
        int lane = (idx >> 3) & 63;
        int t    = idx >> 9;          // 0..287 = j*24 + kc
        int kc   = t % 24;
        int j    = t / 24;
        int g    = j >> 2;
        int n    = (j & 3) * 16 + (lane & 15);
        int k    = kc * 32 + ((lane >> 4) & 3) * 8 + e;
        const float* W = (g == 0) ? Wk : (g == 1) ? Wq : Wv;
        Wf[idx] = f2bf(W[k * HEAD + n]);
    }
}

// ---------------------------------------------------------------------------
// Kernel 1: QKV via MFMA, fully coalesced memory paths.
// 512 blocks x 256 thr (4 waves). Block owns 32 rows x 192 cols (K|Q|V).
// x staged through LDS in 4 K-chunks of 192 floats: dense float4 loads
// (thread-linear over the chunk -> contiguous segments), cvt_pk -> bf16,
// ds_write_b64; A-frags via ds_read_b128 (pitch 200 shorts -> uniform bank
// spread). W-frags are 1KB contiguous loads from the fragment-ordered Wf.
// Wave w: rows (w&1)*16, j-frags (w>>1)*6.. +6. K prescaled by
// 768^-0.5*log2(e).
// ---------------------------------------------------------------------------
__global__ __launch_bounds__(256) void qkv_mfma(
    const float* __restrict__ x, const short* __restrict__ Wf,
    const float* __restrict__ bkp, const float* __restrict__ bqp,
    const float* __restrict__ bvp,
    short* __restrict__ Kb, short* __restrict__ Qb, short* __restrict__ Vt) {
    const float scale2 = 0.052058773f;   // 768^-0.5 * log2(e)
    __shared__ __align__(16) short xs[32][200];   // 25.6 KB, pitch 200

    const int tid  = threadIdx.x;
    const int w    = tid >> 6;
    const int lane = tid & 63;
    const int ln15 = lane & 15, quad = lane >> 4;
    const int rows0 = blockIdx.x * 32;
    const int rw = (w & 1) * 16;          // wave's row offset in tile
    const int jb = (w >> 1) * 6;          // wave's first j-frag

    floatx4 acc[6];
#pragma unroll
    for (int jj = 0; jj < 6; ++jj) acc[jj] = (floatx4){0.f, 0.f, 0.f, 0.f};

    for (int ch = 0; ch < 4; ++ch) {
        // ---- stage 32 rows x 192 floats (chunk ch) -> bf16 LDS ----
        floatx4 stg[6];
#pragma unroll
        for (int i = 0; i < 6; ++i) {
            int o   = i * 1024 + tid * 4;     // linear float idx in 32x192 chunk
            int r   = o / 192;
            int col = o - r * 192;
            stg[i] = *(const floatx4*)(x + (size_t)(rows0 + r) * C_EMB +
                                       ch * 192 + col);
        }
#pragma unroll
        for (int i = 0; i < 6; ++i) {
            int o   = i * 1024 + tid * 4;
            int r   = o / 192;
            int col = o - r * 192;
            unsigned p01, p23;
            asm("v_cvt_pk_bf16_f32 %0, %1, %2" : "=v"(p01) : "v"(stg[i][0]), "v"(stg[i][1]));
            asm("v_cvt_pk_bf16_f32 %0, %1, %2" : "=v"(p23) : "v"(stg[i][2]), "v"(stg[i][3]));
            *(uint2v*)&xs[r][col] = (uint2v){p01, p23};
        }
        __syncthreads();

        // ---- compute 6 K-steps of 32 on this chunk ----
#pragma unroll
        for (int kc2 = 0; kc2 < 6; ++kc2) {
            int kcg = ch * 6 + kc2;
            short8 a = *(const short8*)&xs[rw + ln15][kc2 * 32 + quad * 8];
            short8 wf[6];
#pragma unroll
            for (int jj = 0; jj < 6; ++jj)
                wf[jj] = *(const short8*)(Wf +
                    ((size_t)((jb + jj) * 24 + kcg) * 64 + lane) * 8);
#pragma unroll
            for (int jj = 0; jj < 6; ++jj)
                acc[jj] = __builtin_amdgcn_mfma_f32_16x16x32_bf16(a, wf[jj], acc[jj], 0, 0, 0);
        }
        __syncthreads();
    }

    // ---- epilogue: bias, scale, store K/Q row-major, V transposed ----
#pragma unroll
    for (int jj = 0; jj < 6; ++jj) {
        int j  = jb + jj;
        int g  = j >> 2;
        int nl = (j & 3) * 16 + ln15;
        float bias = (g == 0 ? bkp : g == 1 ? bqp : bvp)[nl];
#pragma unroll
        for (int r = 0; r < 4; ++r) {
            int grow = rows0 + rw + quad * 4 + r;   // C/D row
            float v = acc[jj][r] + bias;
            if (g == 0)      Kb[(size_t)grow * HEAD + nl] = f2bf(v * scale2);
            else if (g == 1) Qb[(size_t)grow * HEAD + nl] = f2bf(v);
            else {
                int b = grow >> 12, t = grow & 4095;
                Vt[((size_t)(b * HEAD + nl) << 12) + t] = f2bf(v);  // V transposed
            }
        }
    }
}

// ---------------------------------------------------------------------------
// Kernel 2: causal attention partial. One wave/block, 32 t-rows/wave,
// s-chunks of FOUR tiles: grid (128 g32, 16 chunks, 4 batches) -> 4352
// useful waves (~17/CU). exp via raw v_exp_f32 (inputs bounded; scale
// folded into K), P->bf16 via v_cvt_pk_bf16_f32. S computed transposed
// (A=Q, B=K loop-invariant); fp32 atomicAdd merge.
// ---------------------------------------------------------------------------
__global__ __launch_bounds__(64) void attn_part(
    const short* __restrict__ Kb, const short* __restrict__ Qb,
    const short* __restrict__ Vt, float* __restrict__ Oacc,
    float* __restrict__ lacc) {
    __shared__ __align__(16) short Ps[32][72];   // [t_loc][s_loc] wave-local

    int lane = threadIdx.x & 63;
    int ln15 = lane & 15, quad = lane >> 4;
    int g32 = blockIdx.x, c = blockIdx.y, b = blockIdx.z;
    int dtile = g32 >> 1;                 // diagonal s-tile (uniform per 32-tile)
    int lo = c * 4;
    if (lo > dtile) return;
    int hi = min(dtile, lo + 3);
    int base = g32 * 32;

    // K B-frags (prescaled), loop-invariant: B[k=h][n=t]
    short8 bk[2][2];
#pragma unroll
    for (int tg = 0; tg < 2; ++tg) {
        const short* kp = Kb + ((size_t)(b * T_SEQ + base + tg * 16 + ln15)) * HEAD + quad * 8;
        bk[tg][0] = *(const short8*)kp;
        bk[tg][1] = *(const short8*)(kp + 32);
    }

    floatx4 o[2][4];
#pragma unroll
    for (int tg = 0; tg < 2; ++tg)
#pragma unroll
        for (int hb = 0; hb < 4; ++hb) o[tg][hb] = (floatx4){0.f, 0.f, 0.f, 0.f};
    float ls[2] = {0.f, 0.f};

    const short* qp = Qb + ((size_t)(b * T_SEQ + lo * 64 + ln15)) * HEAD + quad * 8;
    const short* vp = Vt + (((size_t)(b * HEAD + ln15)) << 12) + lo * 64 + quad * 8;

    for (int st = lo; st <= hi; ++st) {
        // ALL loads upfront: 8 Q frags + 8 V frags (16 KB/wave in flight)
        short8 aq[4][2], bv[4][2];
#pragma unroll
        for (int sb = 0; sb < 4; ++sb) {
            aq[sb][0] = *(const short8*)(qp + sb * 16 * HEAD);
            aq[sb][1] = *(const short8*)(qp + sb * 16 * HEAD + 32);
        }
#pragma unroll
        for (int hb = 0; hb < 4; ++hb) {
            bv[hb][0] = *(const short8*)(vp + ((size_t)hb << 16));
            bv[hb][1] = *(const short8*)(vp + ((size_t)hb << 16) + 32);
        }

        // S^T = Q . K^T : D row = s_loc = sb*16+quad*4+r, col = t_loc = ln15
        floatx4 sacc[4][2];
#pragma unroll
        for (int sb = 0; sb < 4; ++sb)
#pragma unroll
            for (int tg = 0; tg < 2; ++tg) {
                floatx4 z = (floatx4){0.f, 0.f, 0.f, 0.f};
                z = __builtin_amdgcn_mfma_f32_16x16x32_bf16(aq[sb][0], bk[tg][0], z, 0, 0, 0);
                z = __builtin_amdgcn_mfma_f32_16x16x32_bf16(aq[sb][1], bk[tg][1], z, 0, 0, 0);
                sacc[sb][tg] = z;
            }

        // p = exp2(z) (bounded; scale folded into K); mask diag; pack P
        bool diag = (st == dtile);
        int s0 = st * 64;
#pragma unroll
        for (int tg = 0; tg < 2; ++tg) {
            int tgl = base + tg * 16 + ln15;
#pragma unroll
            for (int sb = 0; sb < 4; ++sb) {
                float pv[4];
#pragma unroll
                for (int r = 0; r < 4; ++r) {
                    float p = __builtin_amdgcn_exp2f(sacc[sb][tg][r]);
                    if (diag) {
                        int sg = s0 + sb * 16 + quad * 4 + r;
                        p = (sg > tgl) ? 0.f : p;
                    }
                    pv[r] = p;
                }
                ls[tg] += (pv[0] + pv[1]) + (pv[2] + pv[3]);
                unsigned a01, a23;
                asm("v_cvt_pk_bf16_f32 %0, %1, %2" : "=v"(a01) : "v"(pv[0]), "v"(pv[1]));
                asm("v_cvt_pk_bf16_f32 %0, %1, %2" : "=v"(a23) : "v"(pv[2]), "v"(pv[3]));
                *(uint2v*)&Ps[tg * 16 + ln15][sb * 16 + quad * 4] = (uint2v){a01, a23};
            }
        }
        __asm__ volatile("s_waitcnt lgkmcnt(0)" ::: "memory");
        short8 ap[2][2];
#pragma unroll
        for (int tg = 0; tg < 2; ++tg) {
            ap[tg][0] = *(const short8*)&Ps[tg * 16 + ln15][quad * 8];
            ap[tg][1] = *(const short8*)&Ps[tg * 16 + ln15][32 + quad * 8];
        }

        // O += P . V
#pragma unroll
        for (int tg = 0; tg < 2; ++tg)
#pragma unroll
            for (int hb = 0; hb < 4; ++hb) {
                o[tg][hb] = __builtin_amdgcn_mfma_f32_16x16x32_bf16(ap[tg][0], bv[hb][0], o[tg][hb], 0, 0, 0);
                o[tg][hb] = __builtin_amdgcn_mfma_f32_16x16x32_bf16(ap[tg][1], bv[hb][1], o[tg][hb], 0, 0, 0);
            }

        qp += 64 * HEAD;
        vp += 64;
    }

    // l partial: reduce over quads (lane ln15 holds t = base+tg*16+ln15)
#pragma unroll
    for (int tg = 0; tg < 2; ++tg) {
        float v = ls[tg];
        v += __shfl_xor(v, 16, 64);
        v += __shfl_xor(v, 32, 64);
        if (quad == 0)
            atomicAdd(lacc + (size_t)b * T_SEQ + base + tg * 16 + ln15, v);
    }
#pragma unroll
    for (int tg = 0; tg < 2; ++tg)
#pragma unroll
        for (int r = 0; r < 4; ++r) {
            int t = base + tg * 16 + quad * 4 + r;
#pragma unroll
            for (int hb = 0; hb < 4; ++hb)
                atomicAdd(Oacc + ((size_t)(b * T_SEQ + t)) * HEAD + hb * 16 + ln15,
                          o[tg][hb][r]);
        }
}

// ---------------------------------------------------------------------------
// Kernel 3: out = Oacc / lacc (fp32)
// ---------------------------------------------------------------------------
__global__ __launch_bounds__(256) void attn_div(
    const float* __restrict__ Oacc, const float* __restrict__ lacc,
    float* __restrict__ out) {
    int idx = blockIdx.x * 256 + threadIdx.x;   // 0 .. 1048575
    out[idx] = Oacc[idx] / lacc[idx >> 6];
}

extern "C" void kernel_launch(void* const* d_in, const int* in_sizes, int n_in,
                              void* d_out, int out_size, void* d_ws, size_t ws_size,
                              hipStream_t stream) {
    // Size-based input mapping (order-robust; W's and b's keep internal order)
    const int XSZ = 4 * T_SEQ * C_EMB;   // 12582912
    const int WSZ = C_EMB * HEAD;        // 49152
    const int BSZ = HEAD;                // 64
    const float* x = nullptr;
    const float* W[3] = {nullptr, nullptr, nullptr};
    const float* B[3] = {nullptr, nullptr, nullptr};
    int iw = 0, ib = 0;
    for (int i = 0; i < n_in; ++i) {
        if (in_sizes[i] == XSZ) x = (const float*)d_in[i];
        else if (in_sizes[i] == WSZ && iw < 3) W[iw++] = (const float*)d_in[i];
        else if (in_sizes[i] == BSZ && ib < 3) B[ib++] = (const float*)d_in[i];
    }

    short* ws = (short*)d_ws;
    short* Kb = ws;                               // [16384][64] bf16   2 MB
    short* Qb = Kb + (size_t)4 * T_SEQ * HEAD;    // [16384][64] bf16   2 MB
    short* Vt = Qb + (size_t)4 * T_SEQ * HEAD;    // [4][64][4096] bf16 2 MB
    short* Wf = Vt + (size_t)4 * HEAD * T_SEQ;    // frag-order W bf16  288 KB
    float* Oacc = (float*)(Wf + (size_t)3 * HEAD * C_EMB); // [4][4096][64] 4 MB
    float* lacc = Oacc + (size_t)4 * T_SEQ * HEAD;         // [4][4096] 64 KB

    hipMemsetAsync(Oacc, 0,
                   ((size_t)4 * T_SEQ * HEAD + 4 * T_SEQ) * sizeof(float),
                   stream);
    wt_transpose_kernel<<<96, 256, 0, stream>>>(W[0], W[1], W[2], Wf);
    qkv_mfma<<<512, 256, 0, stream>>>(x, Wf, B[0], B[1], B[2], Kb, Qb, Vt);
    attn_part<<<dim3(128, 16, 4), 64, 0, stream>>>(Kb, Qb, Vt, Oacc, lacc);
    attn_div<<<4096, 256, 0, stream>>>(Oacc, lacc, (float*)d_out);
}

// Round 3
// 155.690 us; speedup vs baseline: 1.3251x; 1.0997x over previous
//
#include <hip/hip_runtime.h>
#include <hip/hip_bf16.h>

#define T_SEQ 4096
#define C_EMB 768
#define HEAD  64

typedef short  short4v __attribute__((ext_vector_type(4)));
typedef short  short8  __attribute__((ext_vector_type(8)));
typedef float  floatx4 __attribute__((ext_vector_type(4)));
typedef unsigned int uint2v __attribute__((ext_vector_type(2)));

static __device__ __forceinline__ short f2bf(float v) {
    __hip_bfloat16 h = __float2bfloat16(v);
    return *reinterpret_cast<short*>(&h);
}

// ---------------------------------------------------------------------------
// Fragment layouts (1 KB per fragment, lane-linear so consumer loads are
// 64 lanes x 16 B CONTIGUOUS):
//   Kf/Qf: fid = t16*2 + kh          (t16 = global_row>>4, kh = h>>5)
//          elem[lane*8+e] = X[row16 = lane&15][h = kh*32 + (lane>>4)*8 + e]
//   Vf:    fid = (s64*4 + hb)*2 + kh2  per batch (b<<18 shorts base)
//          elem[lane*8+e] = V[s = s64*64 + kh2*32 + (lane>>4)*8 + e]
//                             [h = hb*16 + (lane&15)]
// These match the A/B lane mappings of v_mfma_f32_16x16x32_bf16.
// ---------------------------------------------------------------------------

// ---------------------------------------------------------------------------
// Kernel 0: fp32 W[768][64] (x3) -> bf16 Wf in MFMA-FRAGMENT order:
//   Wf[((j*24 + kc)*64 + lane)*8 + e] = bf16(W_g[k][n])
//   g = j>>2, n = (j&3)*16 + (lane&15), k = kc*32 + (lane>>4)*8 + e
// ---------------------------------------------------------------------------
__global__ void wt_transpose_kernel(const float* __restrict__ Wk,
                                    const float* __restrict__ Wq,
                                    const float* __restrict__ Wv,
                                    short* __restrict__ Wf) {
    const int total = 12 * 24 * 64 * 8;   // 147456
    for (int idx = blockIdx.x * blockDim.x + threadIdx.x; idx < total;
         idx += gridDim.x * blockDim.x) {
        int e    = idx & 7;
        int lane = (idx >> 3) & 63;
        int t    = idx >> 9;          // 0..287 = j*24 + kc
        int kc   = t % 24;
        int j    = t / 24;
        int g    = j >> 2;
        int n    = (j & 3) * 16 + (lane & 15);
        int k    = kc * 32 + ((lane >> 4) & 3) * 8 + e;
        const float* W = (g == 0) ? Wk : (g == 1) ? Wq : Wv;
        Wf[idx] = f2bf(W[k * HEAD + n]);
    }
}

// ---------------------------------------------------------------------------
// Kernel 1: QKV via MFMA, fully coalesced memory paths.
// 512 blocks x 256 thr (4 waves). Block owns 32 rows x 192 cols (K|Q|V).
// x staged through LDS in 4 K-chunks; W-frags are 1KB contiguous loads.
// Epilogue stores K/Q/V in FRAGMENT order (see above) - scalar 2B stores,
// same count as before, just different addresses. K prescaled by
// 768^-0.5*log2(e).
// ---------------------------------------------------------------------------
__global__ __launch_bounds__(256) void qkv_mfma(
    const float* __restrict__ x, const short* __restrict__ Wf,
    const float* __restrict__ bkp, const float* __restrict__ bqp,
    const float* __restrict__ bvp,
    short* __restrict__ Kf, short* __restrict__ Qf, short* __restrict__ Vf) {
    const float scale2 = 0.052058773f;   // 768^-0.5 * log2(e)
    __shared__ __align__(16) short xs[32][200];   // 12.8 KB, pitch 200

    const int tid  = threadIdx.x;
    const int w    = tid >> 6;
    const int lane = tid & 63;
    const int ln15 = lane & 15, quad = lane >> 4;
    const int rows0 = blockIdx.x * 32;
    const int rw = (w & 1) * 16;          // wave's row offset in tile
    const int jb = (w >> 1) * 6;          // wave's first j-frag

    floatx4 acc[6];
#pragma unroll
    for (int jj = 0; jj < 6; ++jj) acc[jj] = (floatx4){0.f, 0.f, 0.f, 0.f};

    for (int ch = 0; ch < 4; ++ch) {
        // ---- stage 32 rows x 192 floats (chunk ch) -> bf16 LDS ----
        floatx4 stg[6];
#pragma unroll
        for (int i = 0; i < 6; ++i) {
            int o   = i * 1024 + tid * 4;     // linear float idx in 32x192 chunk
            int r   = o / 192;
            int col = o - r * 192;
            stg[i] = *(const floatx4*)(x + (size_t)(rows0 + r) * C_EMB +
                                       ch * 192 + col);
        }
#pragma unroll
        for (int i = 0; i < 6; ++i) {
            int o   = i * 1024 + tid * 4;
            int r   = o / 192;
            int col = o - r * 192;
            unsigned p01, p23;
            asm("v_cvt_pk_bf16_f32 %0, %1, %2" : "=v"(p01) : "v"(stg[i][0]), "v"(stg[i][1]));
            asm("v_cvt_pk_bf16_f32 %0, %1, %2" : "=v"(p23) : "v"(stg[i][2]), "v"(stg[i][3]));
            *(uint2v*)&xs[r][col] = (uint2v){p01, p23};
        }
        __syncthreads();

        // ---- compute 6 K-steps of 32 on this chunk ----
#pragma unroll
        for (int kc2 = 0; kc2 < 6; ++kc2) {
            int kcg = ch * 6 + kc2;
            short8 a = *(const short8*)&xs[rw + ln15][kc2 * 32 + quad * 8];
            short8 wf[6];
#pragma unroll
            for (int jj = 0; jj < 6; ++jj)
                wf[jj] = *(const short8*)(Wf +
                    ((size_t)((jb + jj) * 24 + kcg) * 64 + lane) * 8);
#pragma unroll
            for (int jj = 0; jj < 6; ++jj)
                acc[jj] = __builtin_amdgcn_mfma_f32_16x16x32_bf16(a, wf[jj], acc[jj], 0, 0, 0);
        }
        __syncthreads();
    }

    // ---- epilogue: bias, scale, store in fragment order ----
#pragma unroll
    for (int jj = 0; jj < 6; ++jj) {
        int j  = jb + jj;
        int g  = j >> 2;
        int nl = (j & 3) * 16 + ln15;        // h in [0,64)
        float bias = (g == 0 ? bkp : g == 1 ? bqp : bvp)[nl];
        int kh = nl >> 5;                    // K/Q frag coords (row-invariant)
        int hq = (nl >> 3) & 3;
        int he = nl & 7;
#pragma unroll
        for (int r = 0; r < 4; ++r) {
            int grow = rows0 + rw + quad * 4 + r;   // global row in [0,16384)
            float v = acc[jj][r] + bias;
            if (g == 0) {
                int t16 = grow >> 4, tr = grow & 15;
                Kf[((size_t)(t16 * 2 + kh)) * 512 + (tr | (hq << 4)) * 8 + he] =
                    f2bf(v * scale2);
            } else if (g == 1) {
                int t16 = grow >> 4, tr = grow & 15;
                Qf[((size_t)(t16 * 2 + kh)) * 512 + (tr | (hq << 4)) * 8 + he] =
                    f2bf(v);
            } else {
                int b = grow >> 12, s = grow & 4095;
                int fid = ((s >> 6) * 4 + (nl >> 4)) * 2 + ((s >> 5) & 1);
                int lc  = (((s >> 3) & 3) << 4) | (nl & 15);
                Vf[((size_t)b << 18) + (size_t)fid * 512 + lc * 8 + (s & 7)] =
                    f2bf(v);
            }
        }
    }
}

// ---------------------------------------------------------------------------
// Kernel 2: causal attention partial. One wave/block, 32 t-rows/wave,
// s-chunks of FOUR tiles: grid (128 g32, 16 chunks, 4 batches) -> 4352
// useful waves. ALL Q/K/V loads are contiguous 1KB wave-loads from the
// fragment-ordered buffers (was: 128B-strided 16B/lane scatter -> TA
// request-rate bound at ~32 line-transactions per load). exp via raw
// v_exp_f32 (scale folded into K), P->bf16 via v_cvt_pk_bf16_f32.
// S computed transposed (A=Q, B=K loop-invariant); fp32 atomicAdd merge.
// ---------------------------------------------------------------------------
__global__ __launch_bounds__(64) void attn_part(
    const short* __restrict__ Kf, const short* __restrict__ Qf,
    const short* __restrict__ Vf, float* __restrict__ Oacc,
    float* __restrict__ lacc) {
    __shared__ __align__(16) short Ps[32][72];   // [t_loc][s_loc] wave-local

    int lane = threadIdx.x & 63;
    int ln15 = lane & 15, quad = lane >> 4;
    int g32 = blockIdx.x, c = blockIdx.y, b = blockIdx.z;
    int dtile = g32 >> 1;                 // diagonal s-tile (uniform per 32-tile)
    int lo = c * 4;
    if (lo > dtile) return;
    int hi = min(dtile, lo + 3);
    int base = g32 * 32;

    // K B-frags (prescaled), loop-invariant — contiguous 1KB loads
    short8 bk[2][2];
    {
        const short* kfp = Kf + ((size_t)(b * 256 + g32 * 2) * 2) * 512 + lane * 8;
#pragma unroll
        for (int tg = 0; tg < 2; ++tg)
#pragma unroll
            for (int kh = 0; kh < 2; ++kh)
                bk[tg][kh] = *(const short8*)(kfp + (tg * 2 + kh) * 512);
    }

    floatx4 o[2][4];
#pragma unroll
    for (int tg = 0; tg < 2; ++tg)
#pragma unroll
        for (int hb = 0; hb < 4; ++hb) o[tg][hb] = (floatx4){0.f, 0.f, 0.f, 0.f};
    float ls[2] = {0.f, 0.f};

    // Q/V fragment pointers: 8 frags (4 KB... 8*512 shorts) per 64-s-tile
    const short* qfp = Qf + ((size_t)(b * 256 + lo * 4) * 2) * 512 + lane * 8;
    const short* vfp = Vf + ((size_t)b << 18) + (size_t)lo * 8 * 512 + lane * 8;

    for (int st = lo; st <= hi; ++st) {
        // ALL loads upfront: 8 Q frags + 8 V frags, each 1KB contiguous
        short8 aq[4][2], bv[4][2];
#pragma unroll
        for (int sb = 0; sb < 4; ++sb)
#pragma unroll
            for (int kh = 0; kh < 2; ++kh)
                aq[sb][kh] = *(const short8*)(qfp + (sb * 2 + kh) * 512);
#pragma unroll
        for (int hb = 0; hb < 4; ++hb)
#pragma unroll
            for (int kh = 0; kh < 2; ++kh)
                bv[hb][kh] = *(const short8*)(vfp + (hb * 2 + kh) * 512);

        // S^T = Q . K^T : D row = s_loc = sb*16+quad*4+r, col = t_loc = ln15
        floatx4 sacc[4][2];
#pragma unroll
        for (int sb = 0; sb < 4; ++sb)
#pragma unroll
            for (int tg = 0; tg < 2; ++tg) {
                floatx4 z = (floatx4){0.f, 0.f, 0.f, 0.f};
                z = __builtin_amdgcn_mfma_f32_16x16x32_bf16(aq[sb][0], bk[tg][0], z, 0, 0, 0);
                z = __builtin_amdgcn_mfma_f32_16x16x32_bf16(aq[sb][1], bk[tg][1], z, 0, 0, 0);
                sacc[sb][tg] = z;
            }

        // p = exp2(z) (bounded; scale folded into K); mask diag; pack P
        bool diag = (st == dtile);
        int s0 = st * 64;
#pragma unroll
        for (int tg = 0; tg < 2; ++tg) {
            int tgl = base + tg * 16 + ln15;
#pragma unroll
            for (int sb = 0; sb < 4; ++sb) {
                float pv[4];
#pragma unroll
                for (int r = 0; r < 4; ++r) {
                    float p = __builtin_amdgcn_exp2f(sacc[sb][tg][r]);
                    if (diag) {
                        int sg = s0 + sb * 16 + quad * 4 + r;
                        p = (sg > tgl) ? 0.f : p;
                    }
                    pv[r] = p;
                }
                ls[tg] += (pv[0] + pv[1]) + (pv[2] + pv[3]);
                unsigned a01, a23;
                asm("v_cvt_pk_bf16_f32 %0, %1, %2" : "=v"(a01) : "v"(pv[0]), "v"(pv[1]));
                asm("v_cvt_pk_bf16_f32 %0, %1, %2" : "=v"(a23) : "v"(pv[2]), "v"(pv[3]));
                *(uint2v*)&Ps[tg * 16 + ln15][sb * 16 + quad * 4] = (uint2v){a01, a23};
            }
        }
        __asm__ volatile("s_waitcnt lgkmcnt(0)" ::: "memory");
        short8 ap[2][2];
#pragma unroll
        for (int tg = 0; tg < 2; ++tg) {
            ap[tg][0] = *(const short8*)&Ps[tg * 16 + ln15][quad * 8];
            ap[tg][1] = *(const short8*)&Ps[tg * 16 + ln15][32 + quad * 8];
        }

        // O += P . V
#pragma unroll
        for (int tg = 0; tg < 2; ++tg)
#pragma unroll
            for (int hb = 0; hb < 4; ++hb) {
                o[tg][hb] = __builtin_amdgcn_mfma_f32_16x16x32_bf16(ap[tg][0], bv[hb][0], o[tg][hb], 0, 0, 0);
                o[tg][hb] = __builtin_amdgcn_mfma_f32_16x16x32_bf16(ap[tg][1], bv[hb][1], o[tg][hb], 0, 0, 0);
            }

        qfp += 8 * 512;
        vfp += 8 * 512;
    }

    // l partial: reduce over quads (lane ln15 holds t = base+tg*16+ln15)
#pragma unroll
    for (int tg = 0; tg < 2; ++tg) {
        float v = ls[tg];
        v += __shfl_xor(v, 16, 64);
        v += __shfl_xor(v, 32, 64);
        if (quad == 0)
            atomicAdd(lacc + (size_t)b * T_SEQ + base + tg * 16 + ln15, v);
    }
#pragma unroll
    for (int tg = 0; tg < 2; ++tg)
#pragma unroll
        for (int r = 0; r < 4; ++r) {
            int t = base + tg * 16 + quad * 4 + r;
#pragma unroll
            for (int hb = 0; hb < 4; ++hb)
                atomicAdd(Oacc + ((size_t)(b * T_SEQ + t)) * HEAD + hb * 16 + ln15,
                          o[tg][hb][r]);
        }
}

// ---------------------------------------------------------------------------
// Kernel 3: out = Oacc / lacc (fp32)
// ---------------------------------------------------------------------------
__global__ __launch_bounds__(256) void attn_div(
    const float* __restrict__ Oacc, const float* __restrict__ lacc,
    float* __restrict__ out) {
    int idx = blockIdx.x * 256 + threadIdx.x;   // 0 .. 1048575
    out[idx] = Oacc[idx] / lacc[idx >> 6];
}

extern "C" void kernel_launch(void* const* d_in, const int* in_sizes, int n_in,
                              void* d_out, int out_size, void* d_ws, size_t ws_size,
                              hipStream_t stream) {
    // Size-based input mapping (order-robust; W's and b's keep internal order)
    const int XSZ = 4 * T_SEQ * C_EMB;   // 12582912
    const int WSZ = C_EMB * HEAD;        // 49152
    const int BSZ = HEAD;                // 64
    const float* x = nullptr;
    const float* W[3] = {nullptr, nullptr, nullptr};
    const float* B[3] = {nullptr, nullptr, nullptr};
    int iw = 0, ib = 0;
    for (int i = 0; i < n_in; ++i) {
        if (in_sizes[i] == XSZ) x = (const float*)d_in[i];
        else if (in_sizes[i] == WSZ && iw < 3) W[iw++] = (const float*)d_in[i];
        else if (in_sizes[i] == BSZ && ib < 3) B[ib++] = (const float*)d_in[i];
    }

    short* ws = (short*)d_ws;
    short* Kf = ws;                               // frag-order K bf16   2 MB
    short* Qf = Kf + (size_t)4 * T_SEQ * HEAD;    // frag-order Q bf16   2 MB
    short* Vf = Qf + (size_t)4 * T_SEQ * HEAD;    // frag-order V bf16   2 MB
    short* Wf = Vf + (size_t)4 * HEAD * T_SEQ;    // frag-order W bf16  288 KB
    float* Oacc = (float*)(Wf + (size_t)3 * HEAD * C_EMB); // [4][4096][64] 4 MB
    float* lacc = Oacc + (size_t)4 * T_SEQ * HEAD;         // [4][4096] 64 KB

    hipMemsetAsync(Oacc, 0,
                   ((size_t)4 * T_SEQ * HEAD + 4 * T_SEQ) * sizeof(float),
                   stream);
    wt_transpose_kernel<<<96, 256, 0, stream>>>(W[0], W[1], W[2], Wf);
    qkv_mfma<<<512, 256, 0, stream>>>(x, Wf, B[0], B[1], B[2], Kf, Qf, Vf);
    attn_part<<<dim3(128, 16, 4), 64, 0, stream>>>(Kf, Qf, Vf, Oacc, lacc);
    attn_div<<<4096, 256, 0, stream>>>(Oacc, lacc, (float*)d_out);
}

// Round 4
// 154.952 us; speedup vs baseline: 1.3314x; 1.0048x over previous
//
#include <hip/hip_runtime.h>
#include <hip/hip_bf16.h>

#define T_SEQ 4096
#define C_EMB 768
#define HEAD  64

typedef short  short4v __attribute__((ext_vector_type(4)));
typedef short  short8  __attribute__((ext_vector_type(8)));
typedef float  floatx4 __attribute__((ext_vector_type(4)));
typedef unsigned int uint2v __attribute__((ext_vector_type(2)));

static __device__ __forceinline__ short f2bf(float v) {
    __hip_bfloat16 h = __float2bfloat16(v);
    return *reinterpret_cast<short*>(&h);
}

// ---------------------------------------------------------------------------
// Fragment layouts (1 KB per fragment, lane-linear so consumer loads are
// 64 lanes x 16 B CONTIGUOUS):
//   Kf/Qf: fid = t16*2 + kh          (t16 = global_row>>4, kh = h>>5)
//          elem[lane*8+e] = X[row16 = lane&15][h = kh*32 + (lane>>4)*8 + e]
//   Vf:    fid = (s64*4 + hb)*2 + kh2  per batch (b<<18 shorts base)
//          elem[lane*8+e] = V[s = s64*64 + kh2*32 + (lane>>4)*8 + e]
//                             [h = hb*16 + (lane&15)]
// ---------------------------------------------------------------------------

// ---------------------------------------------------------------------------
// Kernel 0: fp32 W[768][64] (x3) -> bf16 Wf in MFMA-FRAGMENT order:
//   Wf[((j*24 + kc)*64 + lane)*8 + e] = bf16(W_g[k][n])
// ---------------------------------------------------------------------------
__global__ void wt_transpose_kernel(const float* __restrict__ Wk,
                                    const float* __restrict__ Wq,
                                    const float* __restrict__ Wv,
                                    short* __restrict__ Wf) {
    const int total = 12 * 24 * 64 * 8;   // 147456
    for (int idx = blockIdx.x * blockDim.x + threadIdx.x; idx < total;
         idx += gridDim.x * blockDim.x) {
        int e    = idx & 7;
        int lane = (idx >> 3) & 63;
        int t    = idx >> 9;          // 0..287 = j*24 + kc
        int kc   = t % 24;
        int j    = t / 24;
        int g    = j >> 2;
        int n    = (j & 3) * 16 + (lane & 15);
        int k    = kc * 32 + ((lane >> 4) & 3) * 8 + e;
        const float* W = (g == 0) ? Wk : (g == 1) ? Wq : Wv;
        Wf[idx] = f2bf(W[k * HEAD + n]);
    }
}

// ---------------------------------------------------------------------------
// Kernel 1: QKV via MFMA, fully coalesced memory paths.
// 512 blocks x 256 thr (4 waves). Block owns 32 rows x 192 cols (K|Q|V).
// x staged through LDS; W-frags are 1KB contiguous loads. Epilogue now
// scatters bias/scaled results into LDS in frag-LINEAR order (2B ds_write,
// bank-granular) then block-copies 12KB out as coalesced dwordx4 (was: 24
// scattered 2B global stores/thread = 3.1M TA requests ~ 12us floor).
// K prescaled by 768^-0.5*log2(e).
// ---------------------------------------------------------------------------
__global__ __launch_bounds__(256) void qkv_mfma(
    const float* __restrict__ x, const short* __restrict__ Wf,
    const float* __restrict__ bkp, const float* __restrict__ bqp,
    const float* __restrict__ bvp,
    short* __restrict__ Kf, short* __restrict__ Qf, short* __restrict__ Vf) {
    const float scale2 = 0.052058773f;   // 768^-0.5 * log2(e)
    __shared__ __align__(16) short xs[32][200];   // 12.8 KB, pitch 200

    const int tid  = threadIdx.x;
    const int w    = tid >> 6;
    const int lane = tid & 63;
    const int ln15 = lane & 15, quad = lane >> 4;
    const int rows0 = blockIdx.x * 32;
    const int rw = (w & 1) * 16;          // wave's row offset in tile
    const int jb = (w >> 1) * 6;          // wave's first j-frag

    floatx4 acc[6];
#pragma unroll
    for (int jj = 0; jj < 6; ++jj) acc[jj] = (floatx4){0.f, 0.f, 0.f, 0.f};

    for (int ch = 0; ch < 4; ++ch) {
        // ---- stage 32 rows x 192 floats (chunk ch) -> bf16 LDS ----
        floatx4 stg[6];
#pragma unroll
        for (int i = 0; i < 6; ++i) {
            int o   = i * 1024 + tid * 4;     // linear float idx in 32x192 chunk
            int r   = o / 192;
            int col = o - r * 192;
            stg[i] = *(const floatx4*)(x + (size_t)(rows0 + r) * C_EMB +
                                       ch * 192 + col);
        }
#pragma unroll
        for (int i = 0; i < 6; ++i) {
            int o   = i * 1024 + tid * 4;
            int r   = o / 192;
            int col = o - r * 192;
            unsigned p01, p23;
            asm("v_cvt_pk_bf16_f32 %0, %1, %2" : "=v"(p01) : "v"(stg[i][0]), "v"(stg[i][1]));
            asm("v_cvt_pk_bf16_f32 %0, %1, %2" : "=v"(p23) : "v"(stg[i][2]), "v"(stg[i][3]));
            *(uint2v*)&xs[r][col] = (uint2v){p01, p23};
        }
        __syncthreads();

        // ---- compute 6 K-steps of 32 on this chunk ----
#pragma unroll
        for (int kc2 = 0; kc2 < 6; ++kc2) {
            int kcg = ch * 6 + kc2;
            short8 a = *(const short8*)&xs[rw + ln15][kc2 * 32 + quad * 8];
            short8 wf[6];
#pragma unroll
            for (int jj = 0; jj < 6; ++jj)
                wf[jj] = *(const short8*)(Wf +
                    ((size_t)((jb + jj) * 24 + kcg) * 64 + lane) * 8);
#pragma unroll
            for (int jj = 0; jj < 6; ++jj)
                acc[jj] = __builtin_amdgcn_mfma_f32_16x16x32_bf16(a, wf[jj], acc[jj], 0, 0, 0);
        }
        __syncthreads();   // also guards xs reuse by the epilogue
    }

    // ---- epilogue: bias/scale -> LDS in frag-linear order ----
    // LDS map (shorts): [0,2048) K frags, [2048,4096) Q frags, [4096,6144) V
    short* lds = &xs[0][0];
#pragma unroll
    for (int jj = 0; jj < 6; ++jj) {
        int j  = jb + jj;
        int g  = j >> 2;
        int nl = (j & 3) * 16 + ln15;        // h in [0,64)
        float bias = (g == 0 ? bkp : g == 1 ? bqp : bvp)[nl];
#pragma unroll
        for (int r = 0; r < 4; ++r) {
            int rloc = rw + quad * 4 + r;    // row within block, 0..31
            float v = acc[jj][r] + bias;
            int off;
            short val;
            if (g == 2) {
                val = f2bf(v);
                off = 4096 + ((nl >> 4) << 9) +
                      ((((rloc >> 3) & 3) << 4) | (nl & 15)) * 8 + (rloc & 7);
            } else {
                val = (g == 0) ? f2bf(v * scale2) : f2bf(v);
                int tr = rloc & 15, kh = nl >> 5;
                int hq = (nl >> 3) & 3, he = nl & 7;
                off = (g << 11) + (((rloc >> 4) * 2 + kh) << 9) +
                      (tr | (hq << 4)) * 8 + he;
            }
            lds[off] = val;
        }
    }
    __syncthreads();

    // ---- coalesced copy-out: 768 x 16B chunks, 256 thr x 3 ----
    {
        int bb = rows0 >> 12, s = rows0 & 4095;
        size_t vbase = ((size_t)bb << 18) +
                       ((size_t)((s >> 6) * 8 + ((s >> 5) & 1)) << 9);
#pragma unroll
        for (int cc = 0; cc < 3; ++cc) {
            int i = (cc * 256 + tid) * 8;        // short index 0..6136
            short8 d = *(const short8*)&lds[i];
            if (i < 2048)
                *(short8*)(Kf + (size_t)rows0 * 64 + i) = d;
            else if (i < 4096)
                *(short8*)(Qf + (size_t)rows0 * 64 + (i - 2048)) = d;
            else {
                int iv = i - 4096;
                *(short8*)(Vf + vbase + (size_t)(iv >> 9) * 1024 + (iv & 511)) = d;
            }
        }
    }
}

// ---------------------------------------------------------------------------
// Kernel 2: causal attention partial. One wave/block, 32 t-rows/wave,
// s-chunks of EIGHT tiles (was 4): grid (128 g32, 8 chunks, 4 batches) ->
// 2304 useful waves. Coarser chunks HALVE the O-merge atomic requests
// (8.9M -> 4.8M; atomics never coalesce -> TA request-rate floor). The
// lower occupancy (2.25/SIMD avg) is covered by a register DOUBLE-BUFFERED
// prefetch: next tile's 16 Q/V frag loads are issued before the current
// tile's QK->exp->PV chain. Static A/B buffers via explicit alternation.
// ---------------------------------------------------------------------------
__global__ __launch_bounds__(64) void attn_part(
    const short* __restrict__ Kf, const short* __restrict__ Qf,
    const short* __restrict__ Vf, float* __restrict__ Oacc,
    float* __restrict__ lacc) {
    __shared__ __align__(16) short Ps[32][72];   // [t_loc][s_loc] wave-local

    int lane = threadIdx.x & 63;
    int ln15 = lane & 15, quad = lane >> 4;
    int g32 = blockIdx.x, c = blockIdx.y, b = blockIdx.z;
    int dtile = g32 >> 1;                 // diagonal s-tile (uniform per 32-tile)
    int lo = c * 8;
    if (lo > dtile) return;
    int hi = min(dtile, lo + 7);
    int base = g32 * 32;

    // K B-frags (prescaled), loop-invariant — contiguous 1KB loads
    short8 bk[2][2];
    {
        const short* kfp = Kf + ((size_t)(b * 256 + g32 * 2) * 2) * 512 + lane * 8;
#pragma unroll
        for (int tg = 0; tg < 2; ++tg)
#pragma unroll
            for (int kh = 0; kh < 2; ++kh)
                bk[tg][kh] = *(const short8*)(kfp + (tg * 2 + kh) * 512);
    }

    floatx4 o[2][4];
#pragma unroll
    for (int tg = 0; tg < 2; ++tg)
#pragma unroll
        for (int hb = 0; hb < 4; ++hb) o[tg][hb] = (floatx4){0.f, 0.f, 0.f, 0.f};
    float ls[2] = {0.f, 0.f};

    const short* qfp = Qf + ((size_t)(b * 256 + lo * 4) * 2) * 512 + lane * 8;
    const short* vfp = Vf + ((size_t)b << 18) + (size_t)lo * 8 * 512 + lane * 8;

    short8 aqA[4][2], bvA[4][2], aqB[4][2], bvB[4][2];
    // preload tile lo into A
#pragma unroll
    for (int sb = 0; sb < 4; ++sb)
#pragma unroll
        for (int kh = 0; kh < 2; ++kh)
            aqA[sb][kh] = *(const short8*)(qfp + (sb * 2 + kh) * 512);
#pragma unroll
    for (int hb = 0; hb < 4; ++hb)
#pragma unroll
        for (int kh = 0; kh < 2; ++kh)
            bvA[hb][kh] = *(const short8*)(vfp + (hb * 2 + kh) * 512);

    auto tile_step = [&](short8 (&aq)[4][2], short8 (&bv)[4][2],
                         short8 (&aqn)[4][2], short8 (&bvn)[4][2], int st) {
        // prefetch next tile FIRST (overlaps the whole compute chain)
        if (st < hi) {
            int ti = st + 1 - lo;
#pragma unroll
            for (int sb = 0; sb < 4; ++sb)
#pragma unroll
                for (int kh = 0; kh < 2; ++kh)
                    aqn[sb][kh] = *(const short8*)(qfp + (size_t)ti * 4096 +
                                                   (sb * 2 + kh) * 512);
#pragma unroll
            for (int hb = 0; hb < 4; ++hb)
#pragma unroll
                for (int kh = 0; kh < 2; ++kh)
                    bvn[hb][kh] = *(const short8*)(vfp + (size_t)ti * 4096 +
                                                   (hb * 2 + kh) * 512);
        }

        // S^T = Q . K^T : D row = s_loc = sb*16+quad*4+r, col = t_loc = ln15
        floatx4 sacc[4][2];
#pragma unroll
        for (int sb = 0; sb < 4; ++sb)
#pragma unroll
            for (int tg = 0; tg < 2; ++tg) {
                floatx4 z = (floatx4){0.f, 0.f, 0.f, 0.f};
                z = __builtin_amdgcn_mfma_f32_16x16x32_bf16(aq[sb][0], bk[tg][0], z, 0, 0, 0);
                z = __builtin_amdgcn_mfma_f32_16x16x32_bf16(aq[sb][1], bk[tg][1], z, 0, 0, 0);
                sacc[sb][tg] = z;
            }

        // p = exp2(z) (bounded; scale folded into K); mask diag; pack P
        bool diag = (st == dtile);
        int s0 = st * 64;
#pragma unroll
        for (int tg = 0; tg < 2; ++tg) {
            int tgl = base + tg * 16 + ln15;
#pragma unroll
            for (int sb = 0; sb < 4; ++sb) {
                float pv[4];
#pragma unroll
                for (int r = 0; r < 4; ++r) {
                    float p = __builtin_amdgcn_exp2f(sacc[sb][tg][r]);
                    if (diag) {
                        int sg = s0 + sb * 16 + quad * 4 + r;
                        p = (sg > tgl) ? 0.f : p;
                    }
                    pv[r] = p;
                }
                ls[tg] += (pv[0] + pv[1]) + (pv[2] + pv[3]);
                unsigned a01, a23;
                asm("v_cvt_pk_bf16_f32 %0, %1, %2" : "=v"(a01) : "v"(pv[0]), "v"(pv[1]));
                asm("v_cvt_pk_bf16_f32 %0, %1, %2" : "=v"(a23) : "v"(pv[2]), "v"(pv[3]));
                *(uint2v*)&Ps[tg * 16 + ln15][sb * 16 + quad * 4] = (uint2v){a01, a23};
            }
        }
        __asm__ volatile("s_waitcnt lgkmcnt(0)" ::: "memory");
        short8 ap[2][2];
#pragma unroll
        for (int tg = 0; tg < 2; ++tg) {
            ap[tg][0] = *(const short8*)&Ps[tg * 16 + ln15][quad * 8];
            ap[tg][1] = *(const short8*)&Ps[tg * 16 + ln15][32 + quad * 8];
        }

        // O += P . V
#pragma unroll
        for (int tg = 0; tg < 2; ++tg)
#pragma unroll
            for (int hb = 0; hb < 4; ++hb) {
                o[tg][hb] = __builtin_amdgcn_mfma_f32_16x16x32_bf16(ap[tg][0], bv[hb][0], o[tg][hb], 0, 0, 0);
                o[tg][hb] = __builtin_amdgcn_mfma_f32_16x16x32_bf16(ap[tg][1], bv[hb][1], o[tg][hb], 0, 0, 0);
            }
    };

#pragma unroll
    for (int it = 0; it < 8; it += 2) {
        if (lo + it > hi) break;
        tile_step(aqA, bvA, aqB, bvB, lo + it);
        if (lo + it + 1 > hi) break;
        tile_step(aqB, bvB, aqA, bvA, lo + it + 1);
    }

    // l partial: reduce over quads (lane ln15 holds t = base+tg*16+ln15)
#pragma unroll
    for (int tg = 0; tg < 2; ++tg) {
        float v = ls[tg];
        v += __shfl_xor(v, 16, 64);
        v += __shfl_xor(v, 32, 64);
        if (quad == 0)
            atomicAdd(lacc + (size_t)b * T_SEQ + base + tg * 16 + ln15, v);
    }
#pragma unroll
    for (int tg = 0; tg < 2; ++tg)
#pragma unroll
        for (int r = 0; r < 4; ++r) {
            int t = base + tg * 16 + quad * 4 + r;
#pragma unroll
            for (int hb = 0; hb < 4; ++hb)
                atomicAdd(Oacc + ((size_t)(b * T_SEQ + t)) * HEAD + hb * 16 + ln15,
                          o[tg][hb][r]);
        }
}

// ---------------------------------------------------------------------------
// Kernel 3: out = Oacc / lacc (fp32)
// ---------------------------------------------------------------------------
__global__ __launch_bounds__(256) void attn_div(
    const float* __restrict__ Oacc, const float* __restrict__ lacc,
    float* __restrict__ out) {
    int idx = blockIdx.x * 256 + threadIdx.x;   // 0 .. 1048575
    out[idx] = Oacc[idx] / lacc[idx >> 6];
}

extern "C" void kernel_launch(void* const* d_in, const int* in_sizes, int n_in,
                              void* d_out, int out_size, void* d_ws, size_t ws_size,
                              hipStream_t stream) {
    // Size-based input mapping (order-robust; W's and b's keep internal order)
    const int XSZ = 4 * T_SEQ * C_EMB;   // 12582912
    const int WSZ = C_EMB * HEAD;        // 49152
    const int BSZ = HEAD;                // 64
    const float* x = nullptr;
    const float* W[3] = {nullptr, nullptr, nullptr};
    const float* B[3] = {nullptr, nullptr, nullptr};
    int iw = 0, ib = 0;
    for (int i = 0; i < n_in; ++i) {
        if (in_sizes[i] == XSZ) x = (const float*)d_in[i];
        else if (in_sizes[i] == WSZ && iw < 3) W[iw++] = (const float*)d_in[i];
        else if (in_sizes[i] == BSZ && ib < 3) B[ib++] = (const float*)d_in[i];
    }

    short* ws = (short*)d_ws;
    short* Kf = ws;                               // frag-order K bf16   2 MB
    short* Qf = Kf + (size_t)4 * T_SEQ * HEAD;    // frag-order Q bf16   2 MB
    short* Vf = Qf + (size_t)4 * T_SEQ * HEAD;    // frag-order V bf16   2 MB
    short* Wf = Vf + (size_t)4 * HEAD * T_SEQ;    // frag-order W bf16  288 KB
    float* Oacc = (float*)(Wf + (size_t)3 * HEAD * C_EMB); // [4][4096][64] 4 MB
    float* lacc = Oacc + (size_t)4 * T_SEQ * HEAD;         // [4][4096] 64 KB

    hipMemsetAsync(Oacc, 0,
                   ((size_t)4 * T_SEQ * HEAD + 4 * T_SEQ) * sizeof(float),
                   stream);
    wt_transpose_kernel<<<96, 256, 0, stream>>>(W[0], W[1], W[2], Wf);
    qkv_mfma<<<512, 256, 0, stream>>>(x, Wf, B[0], B[1], B[2], Kf, Qf, Vf);
    attn_part<<<dim3(128, 8, 4), 64, 0, stream>>>(Kf, Qf, Vf, Oacc, lacc);
    attn_div<<<4096, 256, 0, stream>>>(Oacc, lacc, (float*)d_out);
}

// Round 5
// 150.064 us; speedup vs baseline: 1.3748x; 1.0326x over previous
//
#include <hip/hip_runtime.h>
#include <hip/hip_bf16.h>

#define T_SEQ 4096
#define C_EMB 768
#define HEAD  64

typedef short  short4v __attribute__((ext_vector_type(4)));
typedef short  short8  __attribute__((ext_vector_type(8)));
typedef float  floatx4 __attribute__((ext_vector_type(4)));
typedef unsigned int uint2v __attribute__((ext_vector_type(2)));

static __device__ __forceinline__ short f2bf(float v) {
    __hip_bfloat16 h = __float2bfloat16(v);
    return *reinterpret_cast<short*>(&h);
}

// ---------------------------------------------------------------------------
// Fragment layouts (1 KB per fragment, lane-linear so consumer loads are
// 64 lanes x 16 B CONTIGUOUS):
//   Kf/Qf: fid = t16*2 + kh          (t16 = global_row>>4, kh = h>>5)
//          elem[lane*8+e] = X[row16 = lane&15][h = kh*32 + (lane>>4)*8 + e]
//   Vf:    fid = (s64*4 + hb)*2 + kh2  per batch (b<<18 shorts base)
//          elem[lane*8+e] = V[s = s64*64 + kh2*32 + (lane>>4)*8 + e]
//                             [h = hb*16 + (lane&15)]
// ---------------------------------------------------------------------------

// ---------------------------------------------------------------------------
// Kernel 0: fp32 W[768][64] (x3) -> bf16 Wf in MFMA-FRAGMENT order:
//   Wf[((j*24 + kc)*64 + lane)*8 + e] = bf16(W_g[k][n])
// ---------------------------------------------------------------------------
__global__ void wt_transpose_kernel(const float* __restrict__ Wk,
                                    const float* __restrict__ Wq,
                                    const float* __restrict__ Wv,
                                    short* __restrict__ Wf) {
    const int total = 12 * 24 * 64 * 8;   // 147456
    for (int idx = blockIdx.x * blockDim.x + threadIdx.x; idx < total;
         idx += gridDim.x * blockDim.x) {
        int e    = idx & 7;
        int lane = (idx >> 3) & 63;
        int t    = idx >> 9;          // 0..287 = j*24 + kc
        int kc   = t % 24;
        int j    = t / 24;
        int g    = j >> 2;
        int n    = (j & 3) * 16 + (lane & 15);
        int k    = kc * 32 + ((lane >> 4) & 3) * 8 + e;
        const float* W = (g == 0) ? Wk : (g == 1) ? Wq : Wv;
        Wf[idx] = f2bf(W[k * HEAD + n]);
    }
}

// ---------------------------------------------------------------------------
// Kernel 1: QKV via MFMA, fully coalesced memory paths.
// 512 blocks x 256 thr (4 waves). Block owns 32 rows x 192 cols (K|Q|V).
// x staged through LDS; W-frags are 1KB contiguous loads. Epilogue
// scatters into LDS (bank-granular) then block-copies out coalesced.
// K prescaled by 768^-0.5*log2(e).
// ---------------------------------------------------------------------------
__global__ __launch_bounds__(256) void qkv_mfma(
    const float* __restrict__ x, const short* __restrict__ Wf,
    const float* __restrict__ bkp, const float* __restrict__ bqp,
    const float* __restrict__ bvp,
    short* __restrict__ Kf, short* __restrict__ Qf, short* __restrict__ Vf) {
    const float scale2 = 0.052058773f;   // 768^-0.5 * log2(e)
    __shared__ __align__(16) short xs[32][200];   // 12.8 KB, pitch 200

    const int tid  = threadIdx.x;
    const int w    = tid >> 6;
    const int lane = tid & 63;
    const int ln15 = lane & 15, quad = lane >> 4;
    const int rows0 = blockIdx.x * 32;
    const int rw = (w & 1) * 16;          // wave's row offset in tile
    const int jb = (w >> 1) * 6;          // wave's first j-frag

    floatx4 acc[6];
#pragma unroll
    for (int jj = 0; jj < 6; ++jj) acc[jj] = (floatx4){0.f, 0.f, 0.f, 0.f};

    for (int ch = 0; ch < 4; ++ch) {
        // ---- stage 32 rows x 192 floats (chunk ch) -> bf16 LDS ----
        floatx4 stg[6];
#pragma unroll
        for (int i = 0; i < 6; ++i) {
            int o   = i * 1024 + tid * 4;     // linear float idx in 32x192 chunk
            int r   = o / 192;
            int col = o - r * 192;
            stg[i] = *(const floatx4*)(x + (size_t)(rows0 + r) * C_EMB +
                                       ch * 192 + col);
        }
#pragma unroll
        for (int i = 0; i < 6; ++i) {
            int o   = i * 1024 + tid * 4;
            int r   = o / 192;
            int col = o - r * 192;
            unsigned p01, p23;
            asm("v_cvt_pk_bf16_f32 %0, %1, %2" : "=v"(p01) : "v"(stg[i][0]), "v"(stg[i][1]));
            asm("v_cvt_pk_bf16_f32 %0, %1, %2" : "=v"(p23) : "v"(stg[i][2]), "v"(stg[i][3]));
            *(uint2v*)&xs[r][col] = (uint2v){p01, p23};
        }
        __syncthreads();

        // ---- compute 6 K-steps of 32 on this chunk ----
#pragma unroll
        for (int kc2 = 0; kc2 < 6; ++kc2) {
            int kcg = ch * 6 + kc2;
            short8 a = *(const short8*)&xs[rw + ln15][kc2 * 32 + quad * 8];
            short8 wf[6];
#pragma unroll
            for (int jj = 0; jj < 6; ++jj)
                wf[jj] = *(const short8*)(Wf +
                    ((size_t)((jb + jj) * 24 + kcg) * 64 + lane) * 8);
#pragma unroll
            for (int jj = 0; jj < 6; ++jj)
                acc[jj] = __builtin_amdgcn_mfma_f32_16x16x32_bf16(a, wf[jj], acc[jj], 0, 0, 0);
        }
        __syncthreads();   // also guards xs reuse by the epilogue
    }

    // ---- epilogue: bias/scale -> LDS in frag-linear order ----
    // LDS map (shorts): [0,2048) K frags, [2048,4096) Q frags, [4096,6144) V
    short* lds = &xs[0][0];
#pragma unroll
    for (int jj = 0; jj < 6; ++jj) {
        int j  = jb + jj;
        int g  = j >> 2;
        int nl = (j & 3) * 16 + ln15;        // h in [0,64)
        float bias = (g == 0 ? bkp : g == 1 ? bqp : bvp)[nl];
#pragma unroll
        for (int r = 0; r < 4; ++r) {
            int rloc = rw + quad * 4 + r;    // row within block, 0..31
            float v = acc[jj][r] + bias;
            int off;
            short val;
            if (g == 2) {
                val = f2bf(v);
                off = 4096 + ((nl >> 4) << 9) +
                      ((((rloc >> 3) & 3) << 4) | (nl & 15)) * 8 + (rloc & 7);
            } else {
                val = (g == 0) ? f2bf(v * scale2) : f2bf(v);
                int tr = rloc & 15, kh = nl >> 5;
                int hq = (nl >> 3) & 3, he = nl & 7;
                off = (g << 11) + (((rloc >> 4) * 2 + kh) << 9) +
                      (tr | (hq << 4)) * 8 + he;
            }
            lds[off] = val;
        }
    }
    __syncthreads();

    // ---- coalesced copy-out: 768 x 16B chunks, 256 thr x 3 ----
    {
        int bb = rows0 >> 12, s = rows0 & 4095;
        size_t vbase = ((size_t)bb << 18) +
                       ((size_t)((s >> 6) * 8 + ((s >> 5) & 1)) << 9);
#pragma unroll
        for (int cc = 0; cc < 3; ++cc) {
            int i = (cc * 256 + tid) * 8;        // short index 0..6136
            short8 d = *(const short8*)&lds[i];
            if (i < 2048)
                *(short8*)(Kf + (size_t)rows0 * 64 + i) = d;
            else if (i < 4096)
                *(short8*)(Qf + (size_t)rows0 * 64 + (i - 2048)) = d;
            else {
                int iv = i - 4096;
                *(short8*)(Vf + vbase + (size_t)(iv >> 9) * 1024 + (iv & 511)) = d;
            }
        }
    }
}

// ---------------------------------------------------------------------------
// Kernel 2: causal attention partial. One wave/block, 32 t-rows/wave,
// s-chunks of EIGHT tiles, register double-buffered prefetch. Partials go
// to PRIVATE per-chunk slices with plain coalesced stores (was: 4.7M fp32
// global_atomic_add RMWs into a 4MB region shared by all 8 XCDs -> memory-
// side-cache RMW serialization). attn_div sums the <=8 chunk slices.
// ---------------------------------------------------------------------------
__global__ __launch_bounds__(64) void attn_part(
    const short* __restrict__ Kf, const short* __restrict__ Qf,
    const short* __restrict__ Vf, float* __restrict__ Opart,
    float* __restrict__ lpart) {
    __shared__ __align__(16) short Ps[32][72];   // [t_loc][s_loc] wave-local

    int lane = threadIdx.x & 63;
    int ln15 = lane & 15, quad = lane >> 4;
    int g32 = blockIdx.x, c = blockIdx.y, b = blockIdx.z;
    int dtile = g32 >> 1;                 // diagonal s-tile (uniform per 32-tile)
    int lo = c * 8;
    if (lo > dtile) return;
    int hi = min(dtile, lo + 7);
    int base = g32 * 32;

    // K B-frags (prescaled), loop-invariant — contiguous 1KB loads
    short8 bk[2][2];
    {
        const short* kfp = Kf + ((size_t)(b * 256 + g32 * 2) * 2) * 512 + lane * 8;
#pragma unroll
        for (int tg = 0; tg < 2; ++tg)
#pragma unroll
            for (int kh = 0; kh < 2; ++kh)
                bk[tg][kh] = *(const short8*)(kfp + (tg * 2 + kh) * 512);
    }

    floatx4 o[2][4];
#pragma unroll
    for (int tg = 0; tg < 2; ++tg)
#pragma unroll
        for (int hb = 0; hb < 4; ++hb) o[tg][hb] = (floatx4){0.f, 0.f, 0.f, 0.f};
    float ls[2] = {0.f, 0.f};

    const short* qfp = Qf + ((size_t)(b * 256 + lo * 4) * 2) * 512 + lane * 8;
    const short* vfp = Vf + ((size_t)b << 18) + (size_t)lo * 8 * 512 + lane * 8;

    short8 aqA[4][2], bvA[4][2], aqB[4][2], bvB[4][2];
    // preload tile lo into A
#pragma unroll
    for (int sb = 0; sb < 4; ++sb)
#pragma unroll
        for (int kh = 0; kh < 2; ++kh)
            aqA[sb][kh] = *(const short8*)(qfp + (sb * 2 + kh) * 512);
#pragma unroll
    for (int hb = 0; hb < 4; ++hb)
#pragma unroll
        for (int kh = 0; kh < 2; ++kh)
            bvA[hb][kh] = *(const short8*)(vfp + (hb * 2 + kh) * 512);

    auto tile_step = [&](short8 (&aq)[4][2], short8 (&bv)[4][2],
                         short8 (&aqn)[4][2], short8 (&bvn)[4][2], int st) {
        // prefetch next tile FIRST (overlaps the whole compute chain)
        if (st < hi) {
            int ti = st + 1 - lo;
#pragma unroll
            for (int sb = 0; sb < 4; ++sb)
#pragma unroll
                for (int kh = 0; kh < 2; ++kh)
                    aqn[sb][kh] = *(const short8*)(qfp + (size_t)ti * 4096 +
                                                   (sb * 2 + kh) * 512);
#pragma unroll
            for (int hb = 0; hb < 4; ++hb)
#pragma unroll
                for (int kh = 0; kh < 2; ++kh)
                    bvn[hb][kh] = *(const short8*)(vfp + (size_t)ti * 4096 +
                                                   (hb * 2 + kh) * 512);
        }

        // S^T = Q . K^T : D row = s_loc = sb*16+quad*4+r, col = t_loc = ln15
        floatx4 sacc[4][2];
#pragma unroll
        for (int sb = 0; sb < 4; ++sb)
#pragma unroll
            for (int tg = 0; tg < 2; ++tg) {
                floatx4 z = (floatx4){0.f, 0.f, 0.f, 0.f};
                z = __builtin_amdgcn_mfma_f32_16x16x32_bf16(aq[sb][0], bk[tg][0], z, 0, 0, 0);
                z = __builtin_amdgcn_mfma_f32_16x16x32_bf16(aq[sb][1], bk[tg][1], z, 0, 0, 0);
                sacc[sb][tg] = z;
            }

        // p = exp2(z) (bounded; scale folded into K); mask diag; pack P
        bool diag = (st == dtile);
        int s0 = st * 64;
#pragma unroll
        for (int tg = 0; tg < 2; ++tg) {
            int tgl = base + tg * 16 + ln15;
#pragma unroll
            for (int sb = 0; sb < 4; ++sb) {
                float pv[4];
#pragma unroll
                for (int r = 0; r < 4; ++r) {
                    float p = __builtin_amdgcn_exp2f(sacc[sb][tg][r]);
                    if (diag) {
                        int sg = s0 + sb * 16 + quad * 4 + r;
                        p = (sg > tgl) ? 0.f : p;
                    }
                    pv[r] = p;
                }
                ls[tg] += (pv[0] + pv[1]) + (pv[2] + pv[3]);
                unsigned a01, a23;
                asm("v_cvt_pk_bf16_f32 %0, %1, %2" : "=v"(a01) : "v"(pv[0]), "v"(pv[1]));
                asm("v_cvt_pk_bf16_f32 %0, %1, %2" : "=v"(a23) : "v"(pv[2]), "v"(pv[3]));
                *(uint2v*)&Ps[tg * 16 + ln15][sb * 16 + quad * 4] = (uint2v){a01, a23};
            }
        }
        __asm__ volatile("s_waitcnt lgkmcnt(0)" ::: "memory");
        short8 ap[2][2];
#pragma unroll
        for (int tg = 0; tg < 2; ++tg) {
            ap[tg][0] = *(const short8*)&Ps[tg * 16 + ln15][quad * 8];
            ap[tg][1] = *(const short8*)&Ps[tg * 16 + ln15][32 + quad * 8];
        }

        // O += P . V
#pragma unroll
        for (int tg = 0; tg < 2; ++tg)
#pragma unroll
            for (int hb = 0; hb < 4; ++hb) {
                o[tg][hb] = __builtin_amdgcn_mfma_f32_16x16x32_bf16(ap[tg][0], bv[hb][0], o[tg][hb], 0, 0, 0);
                o[tg][hb] = __builtin_amdgcn_mfma_f32_16x16x32_bf16(ap[tg][1], bv[hb][1], o[tg][hb], 0, 0, 0);
            }
    };

#pragma unroll
    for (int it = 0; it < 8; it += 2) {
        if (lo + it > hi) break;
        tile_step(aqA, bvA, aqB, bvB, lo + it);
        if (lo + it + 1 > hi) break;
        tile_step(aqB, bvB, aqA, bvA, lo + it + 1);
    }

    // ---- plain-store merge into private chunk slice (b,c) ----
    float* op = Opart + ((size_t)(b * 8 + c) << 12) * HEAD;
    float* lp = lpart + ((size_t)(b * 8 + c) << 12);

#pragma unroll
    for (int tg = 0; tg < 2; ++tg) {
        float v = ls[tg];
        v += __shfl_xor(v, 16, 64);
        v += __shfl_xor(v, 32, 64);
        if (quad == 0)
            lp[base + tg * 16 + ln15] = v;
    }
#pragma unroll
    for (int tg = 0; tg < 2; ++tg)
#pragma unroll
        for (int r = 0; r < 4; ++r) {
            int t = base + tg * 16 + quad * 4 + r;
#pragma unroll
            for (int hb = 0; hb < 4; ++hb)
                op[(size_t)t * HEAD + hb * 16 + ln15] = o[tg][hb][r];
        }
}

// ---------------------------------------------------------------------------
// Kernel 3: out[b,t,h] = sum_c Opart[b,c,t,h] / sum_c lpart[b,c,t]
// over the nch(t) = (t>>9)+1 chunks that cover row t (chunk c touches
// s-tiles [8c, 8c+7]; contributes iff 8c <= t>>6  <=>  c <= t>>9).
// ---------------------------------------------------------------------------
__global__ __launch_bounds__(256) void attn_div(
    const float* __restrict__ Opart, const float* __restrict__ lpart,
    float* __restrict__ out) {
    int idx = blockIdx.x * 256 + threadIdx.x;   // 0 .. 1048575
    int h = idx & 63;
    int t = (idx >> 6) & 4095;
    int b = idx >> 18;
    int nch = (t >> 9) + 1;
    float os = 0.f, l = 0.f;
    for (int c = 0; c < nch; ++c) {
        size_t s = (size_t)(b * 8 + c) << 12;
        os += Opart[(s + t) * HEAD + h];
        l  += lpart[s + t];
    }
    out[idx] = os / l;
}

extern "C" void kernel_launch(void* const* d_in, const int* in_sizes, int n_in,
                              void* d_out, int out_size, void* d_ws, size_t ws_size,
                              hipStream_t stream) {
    // Size-based input mapping (order-robust; W's and b's keep internal order)
    const int XSZ = 4 * T_SEQ * C_EMB;   // 12582912
    const int WSZ = C_EMB * HEAD;        // 49152
    const int BSZ = HEAD;                // 64
    const float* x = nullptr;
    const float* W[3] = {nullptr, nullptr, nullptr};
    const float* B[3] = {nullptr, nullptr, nullptr};
    int iw = 0, ib = 0;
    for (int i = 0; i < n_in; ++i) {
        if (in_sizes[i] == XSZ) x = (const float*)d_in[i];
        else if (in_sizes[i] == WSZ && iw < 3) W[iw++] = (const float*)d_in[i];
        else if (in_sizes[i] == BSZ && ib < 3) B[ib++] = (const float*)d_in[i];
    }

    short* ws = (short*)d_ws;
    short* Kf = ws;                               // frag-order K bf16   2 MB
    short* Qf = Kf + (size_t)4 * T_SEQ * HEAD;    // frag-order Q bf16   2 MB
    short* Vf = Qf + (size_t)4 * T_SEQ * HEAD;    // frag-order V bf16   2 MB
    short* Wf = Vf + (size_t)4 * HEAD * T_SEQ;    // frag-order W bf16  288 KB
    float* Opart = (float*)(Wf + (size_t)3 * HEAD * C_EMB); // [4][8][4096][64] 32 MB
    float* lpart = Opart + (size_t)32 * T_SEQ * HEAD;       // [4][8][4096] 512 KB

    wt_transpose_kernel<<<96, 256, 0, stream>>>(W[0], W[1], W[2], Wf);
    qkv_mfma<<<512, 256, 0, stream>>>(x, Wf, B[0], B[1], B[2], Kf, Qf, Vf);
    attn_part<<<dim3(128, 8, 4), 64, 0, stream>>>(Kf, Qf, Vf, Opart, lpart);
    attn_div<<<4096, 256, 0, stream>>>(Opart, lpart, (float*)d_out);
}

// Round 9
// 142.219 us; speedup vs baseline: 1.4507x; 1.0552x over previous
//
#include <hip/hip_runtime.h>
#include <hip/hip_bf16.h>

#define T_SEQ 4096
#define C_EMB 768
#define HEAD  64

typedef short  short4v __attribute__((ext_vector_type(4)));
typedef short  short8  __attribute__((ext_vector_type(8)));
typedef float  floatx4 __attribute__((ext_vector_type(4)));
typedef unsigned int uint2v __attribute__((ext_vector_type(2)));

static __device__ __forceinline__ short f2bf(float v) {
    __hip_bfloat16 h = __float2bfloat16(v);
    return *reinterpret_cast<short*>(&h);
}

// ---------------------------------------------------------------------------
// Fragment layouts (1 KB per fragment, lane-linear so consumer loads are
// 64 lanes x 16 B CONTIGUOUS):
//   Kf/Qf: fid = t16*2 + kh          (t16 = global_row>>4, kh = h>>5)
//          elem[lane*8+e] = X[row16 = lane&15][h = kh*32 + (lane>>4)*8 + e]
//   Vf:    fid = (s64*4 + hb)*2 + kh2  per batch (b<<18 shorts base)
//          elem[lane*8+e] = V[s = s64*64 + kh2*32 + (lane>>4)*8 + e]
//                             [h = hb*16 + (lane&15)]
// ---------------------------------------------------------------------------

// ---------------------------------------------------------------------------
// Kernel 0: fp32 W[768][64] (x3) -> bf16 Wf in MFMA-FRAGMENT order:
//   Wf[((j*24 + kc)*64 + lane)*8 + e] = bf16(W_g[k][n])
// ---------------------------------------------------------------------------
__global__ void wt_transpose_kernel(const float* __restrict__ Wk,
                                    const float* __restrict__ Wq,
                                    const float* __restrict__ Wv,
                                    short* __restrict__ Wf) {
    const int total = 12 * 24 * 64 * 8;   // 147456
    for (int idx = blockIdx.x * blockDim.x + threadIdx.x; idx < total;
         idx += gridDim.x * blockDim.x) {
        int e    = idx & 7;
        int lane = (idx >> 3) & 63;
        int t    = idx >> 9;          // 0..287 = j*24 + kc
        int kc   = t % 24;
        int j    = t / 24;
        int g    = j >> 2;
        int n    = (j & 3) * 16 + (lane & 15);
        int k    = kc * 32 + ((lane >> 4) & 3) * 8 + e;
        const float* W = (g == 0) ? Wk : (g == 1) ? Wq : Wv;
        Wf[idx] = f2bf(W[k * HEAD + n]);
    }
}

// ---------------------------------------------------------------------------
// Kernel 1: QKV via MFMA. 512 blocks x **512 thr = 8 waves** (rounds 6-8
// launched 256 thr = 4 waves against an 8-wave decomposition -> j-frags
// 6..11 never computed; THE bisected bug). Block owns 32 rows x 192 cols.
// FULL 768-wide x panel staged to LDS once (48.5 KB), then a 24-step
// barrier-free MFMA loop; wave w: rows (w&1)*16, j-frags (w>>1)*3..+3.
// Epilogue scatters to LDS then copies out coalesced. K prescaled by
// 768^-0.5*log2(e).
// ---------------------------------------------------------------------------
__global__ __launch_bounds__(512) void qkv_mfma(
    const float* __restrict__ x, const short* __restrict__ Wf,
    const float* __restrict__ bkp, const float* __restrict__ bqp,
    const float* __restrict__ bvp,
    short* __restrict__ Kf, short* __restrict__ Qf, short* __restrict__ Vf) {
    const float scale2 = 0.052058773f;   // 768^-0.5 * log2(e)
    __shared__ __align__(16) short xs[32][776];   // 48.5 KB

    const int tid  = threadIdx.x;        // 0..511
    const int w    = tid >> 6;           // 0..7 (8 waves)
    const int lane = tid & 63;
    const int ln15 = lane & 15, quad = lane >> 4;
    const int rows0 = blockIdx.x * 32;
    const int rw = (w & 1) * 16;         // wave's row offset in tile
    const int jb = (w >> 1) * 3;         // wave's first j-frag (3 each, 0..11)

    // ---- stage 32 rows x 768 floats -> bf16 LDS (2 batches of 6 strips) ----
#pragma unroll
    for (int grp = 0; grp < 2; ++grp) {
        floatx4 stg[6];
#pragma unroll
        for (int i = 0; i < 6; ++i) {
            int o = (grp * 6 + i) * 2048 + tid * 4;   // linear float idx 32x768
            int r = o / 768, col = o - r * 768;        // 768%4==0: no straddle
            stg[i] = *(const floatx4*)(x + (size_t)(rows0 + r) * C_EMB + col);
        }
#pragma unroll
        for (int i = 0; i < 6; ++i) {
            int o = (grp * 6 + i) * 2048 + tid * 4;
            int r = o / 768, col = o - r * 768;
            unsigned p01, p23;
            asm("v_cvt_pk_bf16_f32 %0, %1, %2" : "=v"(p01) : "v"(stg[i][0]), "v"(stg[i][1]));
            asm("v_cvt_pk_bf16_f32 %0, %1, %2" : "=v"(p23) : "v"(stg[i][2]), "v"(stg[i][3]));
            *(uint2v*)&xs[r][col] = (uint2v){p01, p23};
        }
    }
    __syncthreads();

    const short* wp[3];
#pragma unroll
    for (int j0 = 0; j0 < 3; ++j0)
        wp[j0] = Wf + ((size_t)((jb + j0) * 24) * 64 + lane) * 8;

    floatx4 acc[3];
#pragma unroll
    for (int jj = 0; jj < 3; ++jj) acc[jj] = (floatx4){0.f, 0.f, 0.f, 0.f};

    // ---- 24 K-steps, no barriers ----
#pragma unroll
    for (int kc = 0; kc < 24; ++kc) {
        short8 a = *(const short8*)&xs[rw + ln15][kc * 32 + quad * 8];
        short8 wf[3];
#pragma unroll
        for (int jj = 0; jj < 3; ++jj)
            wf[jj] = *(const short8*)(wp[jj] + kc * 512);
#pragma unroll
        for (int jj = 0; jj < 3; ++jj)
            acc[jj] = __builtin_amdgcn_mfma_f32_16x16x32_bf16(a, wf[jj], acc[jj], 0, 0, 0);
    }
    __syncthreads();   // xs reused by epilogue scatter

    // ---- epilogue: bias/scale -> LDS in frag-linear order ----
    // LDS map (shorts): [0,2048) K frags, [2048,4096) Q frags, [4096,6144) V
    short* lds = &xs[0][0];
#pragma unroll
    for (int jj = 0; jj < 3; ++jj) {
        int j  = jb + jj;
        int g  = j >> 2;
        int nl = (j & 3) * 16 + ln15;        // h in [0,64)
        float bias = (g == 0 ? bkp : g == 1 ? bqp : bvp)[nl];
#pragma unroll
        for (int r = 0; r < 4; ++r) {
            int rloc = rw + quad * 4 + r;    // row within block, 0..31
            float v = acc[jj][r] + bias;
            int off;
            short val;
            if (g == 2) {
                val = f2bf(v);
                off = 4096 + ((nl >> 4) << 9) +
                      ((((rloc >> 3) & 3) << 4) | (nl & 15)) * 8 + (rloc & 7);
            } else {
                val = (g == 0) ? f2bf(v * scale2) : f2bf(v);
                int tr = rloc & 15, kh = nl >> 5;
                int hq = (nl >> 3) & 3, he = nl & 7;
                off = (g << 11) + (((rloc >> 4) * 2 + kh) << 9) +
                      (tr | (hq << 4)) * 8 + he;
            }
            lds[off] = val;
        }
    }
    __syncthreads();

    // ---- coalesced copy-out: 768 x 16B chunks, 512 thr x 2 (tail guarded) ----
    {
        int bb = rows0 >> 12, s = rows0 & 4095;
        size_t vbase = ((size_t)bb << 18) +
                       ((size_t)((s >> 6) * 8 + ((s >> 5) & 1)) << 9);
#pragma unroll
        for (int cc = 0; cc < 2; ++cc) {
            int i = (cc * 512 + tid) * 8;        // short index 0..8184
            if (i < 6144) {
                short8 d = *(const short8*)&lds[i];
                if (i < 2048)
                    *(short8*)(Kf + (size_t)rows0 * 64 + i) = d;
                else if (i < 4096)
                    *(short8*)(Qf + (size_t)rows0 * 64 + (i - 2048)) = d;
                else {
                    int iv = i - 4096;
                    *(short8*)(Vf + vbase + (size_t)(iv >> 9) * 1024 + (iv & 511)) = d;
                }
            }
        }
    }
}

// ---------------------------------------------------------------------------
// Kernel 2: ROUND-5 PROVEN VERSION, verbatim. Causal attention partial.
// One wave/block, 32 t-rows/wave, s-chunks of EIGHT tiles, register
// double-buffered prefetch. Per-tile: pack P -> LDS, explicit
// s_waitcnt lgkmcnt(0)+"memory" fence, read P frags, PV. Partials to
// private per-chunk slices with plain coalesced stores.
// ---------------------------------------------------------------------------
__global__ __launch_bounds__(64) void attn_part(
    const short* __restrict__ Kf, const short* __restrict__ Qf,
    const short* __restrict__ Vf, float* __restrict__ Opart,
    float* __restrict__ lpart) {
    __shared__ __align__(16) short Ps[32][72];   // [t_loc][s_loc] wave-local

    int lane = threadIdx.x & 63;
    int ln15 = lane & 15, quad = lane >> 4;
    int g32 = blockIdx.x, c = blockIdx.y, b = blockIdx.z;
    int dtile = g32 >> 1;                 // diagonal s-tile
    int lo = c * 8;
    if (lo > dtile) return;
    int hi = min(dtile, lo + 7);
    int base = g32 * 32;

    // K B-frags (prescaled), loop-invariant — contiguous 1KB loads
    short8 bk[2][2];
    {
        const short* kfp = Kf + ((size_t)(b * 256 + g32 * 2) * 2) * 512 + lane * 8;
#pragma unroll
        for (int tg = 0; tg < 2; ++tg)
#pragma unroll
            for (int kh = 0; kh < 2; ++kh)
                bk[tg][kh] = *(const short8*)(kfp + (tg * 2 + kh) * 512);
    }

    floatx4 o[2][4];
#pragma unroll
    for (int tg = 0; tg < 2; ++tg)
#pragma unroll
        for (int hb = 0; hb < 4; ++hb) o[tg][hb] = (floatx4){0.f, 0.f, 0.f, 0.f};
    float ls[2] = {0.f, 0.f};

    const short* qfp = Qf + ((size_t)(b * 256 + lo * 4) * 2) * 512 + lane * 8;
    const short* vfp = Vf + ((size_t)b << 18) + (size_t)lo * 8 * 512 + lane * 8;

    short8 aqA[4][2], bvA[4][2], aqB[4][2], bvB[4][2];
    // preload tile lo into A
#pragma unroll
    for (int sb = 0; sb < 4; ++sb)
#pragma unroll
        for (int kh = 0; kh < 2; ++kh)
            aqA[sb][kh] = *(const short8*)(qfp + (sb * 2 + kh) * 512);
#pragma unroll
    for (int hb = 0; hb < 4; ++hb)
#pragma unroll
        for (int kh = 0; kh < 2; ++kh)
            bvA[hb][kh] = *(const short8*)(vfp + (hb * 2 + kh) * 512);

    auto tile_step = [&](short8 (&aq)[4][2], short8 (&bv)[4][2],
                         short8 (&aqn)[4][2], short8 (&bvn)[4][2], int st) {
        // prefetch next tile FIRST (overlaps the whole compute chain)
        if (st < hi) {
            int ti = st + 1 - lo;
#pragma unroll
            for (int sb = 0; sb < 4; ++sb)
#pragma unroll
                for (int kh = 0; kh < 2; ++kh)
                    aqn[sb][kh] = *(const short8*)(qfp + (size_t)ti * 4096 +
                                                   (sb * 2 + kh) * 512);
#pragma unroll
            for (int hb = 0; hb < 4; ++hb)
#pragma unroll
                for (int kh = 0; kh < 2; ++kh)
                    bvn[hb][kh] = *(const short8*)(vfp + (size_t)ti * 4096 +
                                                   (hb * 2 + kh) * 512);
        }

        // S^T = Q . K^T : D row = s_loc = sb*16+quad*4+r, col = t_loc = ln15
        floatx4 sacc[4][2];
#pragma unroll
        for (int sb = 0; sb < 4; ++sb)
#pragma unroll
            for (int tg = 0; tg < 2; ++tg) {
                floatx4 z = (floatx4){0.f, 0.f, 0.f, 0.f};
                z = __builtin_amdgcn_mfma_f32_16x16x32_bf16(aq[sb][0], bk[tg][0], z, 0, 0, 0);
                z = __builtin_amdgcn_mfma_f32_16x16x32_bf16(aq[sb][1], bk[tg][1], z, 0, 0, 0);
                sacc[sb][tg] = z;
            }

        // p = exp2(z) (bounded; scale folded into K); mask diag; pack P
        bool diag = (st == dtile);
        int s0 = st * 64;
#pragma unroll
        for (int tg = 0; tg < 2; ++tg) {
            int tgl = base + tg * 16 + ln15;
#pragma unroll
            for (int sb = 0; sb < 4; ++sb) {
                float pv4[4];
#pragma unroll
                for (int r = 0; r < 4; ++r) {
                    float p = __builtin_amdgcn_exp2f(sacc[sb][tg][r]);
                    if (diag) {
                        int sg = s0 + sb * 16 + quad * 4 + r;
                        p = (sg > tgl) ? 0.f : p;
                    }
                    pv4[r] = p;
                }
                ls[tg] += (pv4[0] + pv4[1]) + (pv4[2] + pv4[3]);
                unsigned a01, a23;
                asm("v_cvt_pk_bf16_f32 %0, %1, %2" : "=v"(a01) : "v"(pv4[0]), "v"(pv4[1]));
                asm("v_cvt_pk_bf16_f32 %0, %1, %2" : "=v"(a23) : "v"(pv4[2]), "v"(pv4[3]));
                *(uint2v*)&Ps[tg * 16 + ln15][sb * 16 + quad * 4] = (uint2v){a01, a23};
            }
        }
        // cross-lane LDS RAW: fence is mandatory (round-2..5 proven)
        __asm__ volatile("s_waitcnt lgkmcnt(0)" ::: "memory");
        short8 ap[2][2];
#pragma unroll
        for (int tg = 0; tg < 2; ++tg) {
            ap[tg][0] = *(const short8*)&Ps[tg * 16 + ln15][quad * 8];
            ap[tg][1] = *(const short8*)&Ps[tg * 16 + ln15][32 + quad * 8];
        }

        // O += P . V
#pragma unroll
        for (int tg = 0; tg < 2; ++tg)
#pragma unroll
            for (int hb = 0; hb < 4; ++hb) {
                o[tg][hb] = __builtin_amdgcn_mfma_f32_16x16x32_bf16(ap[tg][0], bv[hb][0], o[tg][hb], 0, 0, 0);
                o[tg][hb] = __builtin_amdgcn_mfma_f32_16x16x32_bf16(ap[tg][1], bv[hb][1], o[tg][hb], 0, 0, 0);
            }
    };

#pragma unroll
    for (int it = 0; it < 8; it += 2) {
        if (lo + it > hi) break;
        tile_step(aqA, bvA, aqB, bvB, lo + it);
        if (lo + it + 1 > hi) break;
        tile_step(aqB, bvB, aqA, bvA, lo + it + 1);
    }

    // ---- plain-store merge into private chunk slice (b,c) ----
    float* op = Opart + ((size_t)(b * 8 + c) << 12) * HEAD;
    float* lp = lpart + ((size_t)(b * 8 + c) << 12);

#pragma unroll
    for (int tg = 0; tg < 2; ++tg) {
        float v = ls[tg];
        v += __shfl_xor(v, 16, 64);
        v += __shfl_xor(v, 32, 64);
        if (quad == 0)
            lp[base + tg * 16 + ln15] = v;
    }
#pragma unroll
    for (int tg = 0; tg < 2; ++tg)
#pragma unroll
        for (int r = 0; r < 4; ++r) {
            int t = base + tg * 16 + quad * 4 + r;
#pragma unroll
            for (int hb = 0; hb < 4; ++hb)
                op[(size_t)t * HEAD + hb * 16 + ln15] = o[tg][hb][r];
        }
}

// ---------------------------------------------------------------------------
// Kernel 3: out[b,t,h] = sum_c Opart[b,c,t,h] / sum_c lpart[b,c,t]
// chunk c covers s-tiles [8c,8c+7]; contributes iff c <= t>>9.
// ---------------------------------------------------------------------------
__global__ __launch_bounds__(256) void attn_div(
    const float* __restrict__ Opart, const float* __restrict__ lpart,
    float* __restrict__ out) {
    int idx = blockIdx.x * 256 + threadIdx.x;   // 0 .. 1048575
    int h = idx & 63;
    int t = (idx >> 6) & 4095;
    int b = idx >> 18;
    int nch = (t >> 9) + 1;
    float os = 0.f, l = 0.f;
    for (int c = 0; c < nch; ++c) {
        size_t s = (size_t)(b * 8 + c) << 12;
        os += Opart[(s + t) * HEAD + h];
        l  += lpart[s + t];
    }
    out[idx] = os / l;
}

extern "C" void kernel_launch(void* const* d_in, const int* in_sizes, int n_in,
                              void* d_out, int out_size, void* d_ws, size_t ws_size,
                              hipStream_t stream) {
    // Size-based input mapping (order-robust; W's and b's keep internal order)
    const int XSZ = 4 * T_SEQ * C_EMB;   // 12582912
    const int WSZ = C_EMB * HEAD;        // 49152
    const int BSZ = HEAD;                // 64
    const float* x = nullptr;
    const float* W[3] = {nullptr, nullptr, nullptr};
    const float* B[3] = {nullptr, nullptr, nullptr};
    int iw = 0, ib = 0;
    for (int i = 0; i < n_in; ++i) {
        if (in_sizes[i] == XSZ) x = (const float*)d_in[i];
        else if (in_sizes[i] == WSZ && iw < 3) W[iw++] = (const float*)d_in[i];
        else if (in_sizes[i] == BSZ && ib < 3) B[ib++] = (const float*)d_in[i];
    }

    short* ws = (short*)d_ws;
    short* Kf = ws;                               // frag-order K bf16   2 MB
    short* Qf = Kf + (size_t)4 * T_SEQ * HEAD;    // frag-order Q bf16   2 MB
    short* Vf = Qf + (size_t)4 * T_SEQ * HEAD;    // frag-order V bf16   2 MB
    short* Wf = Vf + (size_t)4 * HEAD * T_SEQ;    // frag-order W bf16  288 KB
    float* Opart = (float*)(Wf + (size_t)3 * HEAD * C_EMB); // [4][8][4096][64] 32 MB
    float* lpart = Opart + (size_t)32 * T_SEQ * HEAD;       // [4][8][4096] 512 KB

    wt_transpose_kernel<<<96, 256, 0, stream>>>(W[0], W[1], W[2], Wf);
    qkv_mfma<<<512, 512, 0, stream>>>(x, Wf, B[0], B[1], B[2], Kf, Qf, Vf);
    attn_part<<<dim3(128, 8, 4), 64, 0, stream>>>(Kf, Qf, Vf, Opart, lpart);
    attn_div<<<4096, 256, 0, stream>>>(Opart, lpart, (float*)d_out);
}

// Round 10
// 137.180 us; speedup vs baseline: 1.5039x; 1.0367x over previous
//
#include <hip/hip_runtime.h>
#include <hip/hip_bf16.h>

#define T_SEQ 4096
#define C_EMB 768
#define HEAD  64

typedef short  short4v __attribute__((ext_vector_type(4)));
typedef short  short8  __attribute__((ext_vector_type(8)));
typedef float  floatx4 __attribute__((ext_vector_type(4)));
typedef unsigned int uint2v __attribute__((ext_vector_type(2)));

static __device__ __forceinline__ short f2bf(float v) {
    __hip_bfloat16 h = __float2bfloat16(v);
    return *reinterpret_cast<short*>(&h);
}

// ---------------------------------------------------------------------------
// Fragment layouts (1 KB per fragment, lane-linear so consumer loads are
// 64 lanes x 16 B CONTIGUOUS):
//   Kf/Qf: fid = t16*2 + kh          (t16 = global_row>>4, kh = h>>5)
//          elem[lane*8+e] = X[row16 = lane&15][h = kh*32 + (lane>>4)*8 + e]
//   Vf:    fid = (s64*4 + hb)*2 + kh2  per batch (b<<18 shorts base)
//          elem[lane*8+e] = V[s = s64*64 + kh2*32 + (lane>>4)*8 + e]
//                             [h = hb*16 + (lane&15)]
// ---------------------------------------------------------------------------

// ---------------------------------------------------------------------------
// Kernel 0: fp32 W[768][64] (x3) -> bf16 Wf in MFMA-FRAGMENT order:
//   Wf[((j*24 + kc)*64 + lane)*8 + e] = bf16(W_g[k][n])
// ---------------------------------------------------------------------------
__global__ void wt_transpose_kernel(const float* __restrict__ Wk,
                                    const float* __restrict__ Wq,
                                    const float* __restrict__ Wv,
                                    short* __restrict__ Wf) {
    const int total = 12 * 24 * 64 * 8;   // 147456
    for (int idx = blockIdx.x * blockDim.x + threadIdx.x; idx < total;
         idx += gridDim.x * blockDim.x) {
        int e    = idx & 7;
        int lane = (idx >> 3) & 63;
        int t    = idx >> 9;          // 0..287 = j*24 + kc
        int kc   = t % 24;
        int j    = t / 24;
        int g    = j >> 2;
        int n    = (j & 3) * 16 + (lane & 15);
        int k    = kc * 32 + ((lane >> 4) & 3) * 8 + e;
        const float* W = (g == 0) ? Wk : (g == 1) ? Wq : Wv;
        Wf[idx] = f2bf(W[k * HEAD + n]);
    }
}

// ---------------------------------------------------------------------------
// Kernel 1: QKV via MFMA (GREEN round-9 version, verbatim). 512 blocks x
// 512 thr = 8 waves. Block owns 32 rows x 192 cols. Full 768-wide x panel
// staged to LDS once (48.5 KB), 24-step barrier-free MFMA loop; wave w:
// rows (w&1)*16, j-frags (w>>1)*3..+3. Epilogue scatters to LDS then
// copies out coalesced. K prescaled by 768^-0.5*log2(e).
// ---------------------------------------------------------------------------
__global__ __launch_bounds__(512) void qkv_mfma(
    const float* __restrict__ x, const short* __restrict__ Wf,
    const float* __restrict__ bkp, const float* __restrict__ bqp,
    const float* __restrict__ bvp,
    short* __restrict__ Kf, short* __restrict__ Qf, short* __restrict__ Vf) {
    const float scale2 = 0.052058773f;   // 768^-0.5 * log2(e)
    __shared__ __align__(16) short xs[32][776];   // 48.5 KB

    const int tid  = threadIdx.x;        // 0..511
    const int w    = tid >> 6;           // 0..7 (8 waves)
    const int lane = tid & 63;
    const int ln15 = lane & 15, quad = lane >> 4;
    const int rows0 = blockIdx.x * 32;
    const int rw = (w & 1) * 16;         // wave's row offset in tile
    const int jb = (w >> 1) * 3;         // wave's first j-frag (3 each, 0..11)

    // ---- stage 32 rows x 768 floats -> bf16 LDS (2 batches of 6 strips) ----
#pragma unroll
    for (int grp = 0; grp < 2; ++grp) {
        floatx4 stg[6];
#pragma unroll
        for (int i = 0; i < 6; ++i) {
            int o = (grp * 6 + i) * 2048 + tid * 4;   // linear float idx 32x768
            int r = o / 768, col = o - r * 768;        // 768%4==0: no straddle
            stg[i] = *(const floatx4*)(x + (size_t)(rows0 + r) * C_EMB + col);
        }
#pragma unroll
        for (int i = 0; i < 6; ++i) {
            int o = (grp * 6 + i) * 2048 + tid * 4;
            int r = o / 768, col = o - r * 768;
            unsigned p01, p23;
            asm("v_cvt_pk_bf16_f32 %0, %1, %2" : "=v"(p01) : "v"(stg[i][0]), "v"(stg[i][1]));
            asm("v_cvt_pk_bf16_f32 %0, %1, %2" : "=v"(p23) : "v"(stg[i][2]), "v"(stg[i][3]));
            *(uint2v*)&xs[r][col] = (uint2v){p01, p23};
        }
    }
    __syncthreads();

    const short* wp[3];
#pragma unroll
    for (int j0 = 0; j0 < 3; ++j0)
        wp[j0] = Wf + ((size_t)((jb + j0) * 24) * 64 + lane) * 8;

    floatx4 acc[3];
#pragma unroll
    for (int jj = 0; jj < 3; ++jj) acc[jj] = (floatx4){0.f, 0.f, 0.f, 0.f};

    // ---- 24 K-steps, no barriers ----
#pragma unroll
    for (int kc = 0; kc < 24; ++kc) {
        short8 a = *(const short8*)&xs[rw + ln15][kc * 32 + quad * 8];
        short8 wf[3];
#pragma unroll
        for (int jj = 0; jj < 3; ++jj)
            wf[jj] = *(const short8*)(wp[jj] + kc * 512);
#pragma unroll
        for (int jj = 0; jj < 3; ++jj)
            acc[jj] = __builtin_amdgcn_mfma_f32_16x16x32_bf16(a, wf[jj], acc[jj], 0, 0, 0);
    }
    __syncthreads();   // xs reused by epilogue scatter

    // ---- epilogue: bias/scale -> LDS in frag-linear order ----
    // LDS map (shorts): [0,2048) K frags, [2048,4096) Q frags, [4096,6144) V
    short* lds = &xs[0][0];
#pragma unroll
    for (int jj = 0; jj < 3; ++jj) {
        int j  = jb + jj;
        int g  = j >> 2;
        int nl = (j & 3) * 16 + ln15;        // h in [0,64)
        float bias = (g == 0 ? bkp : g == 1 ? bqp : bvp)[nl];
#pragma unroll
        for (int r = 0; r < 4; ++r) {
            int rloc = rw + quad * 4 + r;    // row within block, 0..31
            float v = acc[jj][r] + bias;
            int off;
            short val;
            if (g == 2) {
                val = f2bf(v);
                off = 4096 + ((nl >> 4) << 9) +
                      ((((rloc >> 3) & 3) << 4) | (nl & 15)) * 8 + (rloc & 7);
            } else {
                val = (g == 0) ? f2bf(v * scale2) : f2bf(v);
                int tr = rloc & 15, kh = nl >> 5;
                int hq = (nl >> 3) & 3, he = nl & 7;
                off = (g << 11) + (((rloc >> 4) * 2 + kh) << 9) +
                      (tr | (hq << 4)) * 8 + he;
            }
            lds[off] = val;
        }
    }
    __syncthreads();

    // ---- coalesced copy-out: 768 x 16B chunks, 512 thr x 2 (tail guarded) ----
    {
        int bb = rows0 >> 12, s = rows0 & 4095;
        size_t vbase = ((size_t)bb << 18) +
                       ((size_t)((s >> 6) * 8 + ((s >> 5) & 1)) << 9);
#pragma unroll
        for (int cc = 0; cc < 2; ++cc) {
            int i = (cc * 512 + tid) * 8;        // short index 0..8184
            if (i < 6144) {
                short8 d = *(const short8*)&lds[i];
                if (i < 2048)
                    *(short8*)(Kf + (size_t)rows0 * 64 + i) = d;
                else if (i < 4096)
                    *(short8*)(Qf + (size_t)rows0 * 64 + (i - 2048)) = d;
                else {
                    int iv = i - 4096;
                    *(short8*)(Vf + vbase + (size_t)(iv >> 9) * 1024 + (iv & 511)) = d;
                }
            }
        }
    }
}

// ---------------------------------------------------------------------------
// Kernel 2: causal attention partial. CHUNK-4 decomposition (grid
// (128,16,4) -> 4352 useful waves, max 4-tile serial chains) with the
// round-2-proven simple tile body: ALL 16 Q/V frag loads upfront (no
// register double-buffer -> VGPR ~84, 6 waves/SIMD headroom; round-9's
// dbuf was 144 VGPR). Per-tile: QK -> exp/pack P -> LDS, explicit
// s_waitcnt lgkmcnt(0)+"memory" fence (cross-lane LDS RAW), read P, PV.
// Plain-store merge into private per-chunk slice (b*16+c).
// ---------------------------------------------------------------------------
__global__ __launch_bounds__(64) void attn_part(
    const short* __restrict__ Kf, const short* __restrict__ Qf,
    const short* __restrict__ Vf, float* __restrict__ Opart,
    float* __restrict__ lpart) {
    __shared__ __align__(16) short Ps[32][72];   // [t_loc][s_loc] wave-local

    int lane = threadIdx.x & 63;
    int ln15 = lane & 15, quad = lane >> 4;
    int g32 = blockIdx.x, c = blockIdx.y, b = blockIdx.z;
    int dtile = g32 >> 1;                 // diagonal s-tile
    int lo = c * 4;
    if (lo > dtile) return;
    int hi = min(dtile, lo + 3);
    int base = g32 * 32;

    // K B-frags (prescaled), loop-invariant — contiguous 1KB loads
    short8 bk[2][2];
    {
        const short* kfp = Kf + ((size_t)(b * 256 + g32 * 2) * 2) * 512 + lane * 8;
#pragma unroll
        for (int tg = 0; tg < 2; ++tg)
#pragma unroll
            for (int kh = 0; kh < 2; ++kh)
                bk[tg][kh] = *(const short8*)(kfp + (tg * 2 + kh) * 512);
    }

    floatx4 o[2][4];
#pragma unroll
    for (int tg = 0; tg < 2; ++tg)
#pragma unroll
        for (int hb = 0; hb < 4; ++hb) o[tg][hb] = (floatx4){0.f, 0.f, 0.f, 0.f};
    float ls[2] = {0.f, 0.f};

    const short* qfp = Qf + ((size_t)(b * 256 + lo * 4) * 2) * 512 + lane * 8;
    const short* vfp = Vf + ((size_t)b << 18) + (size_t)lo * 8 * 512 + lane * 8;

    for (int st = lo; st <= hi; ++st) {
        // ALL loads upfront: 8 Q frags + 8 V frags, each 1KB contiguous
        short8 aq[4][2], bv[4][2];
#pragma unroll
        for (int sb = 0; sb < 4; ++sb)
#pragma unroll
            for (int kh = 0; kh < 2; ++kh)
                aq[sb][kh] = *(const short8*)(qfp + (sb * 2 + kh) * 512);
#pragma unroll
        for (int hb = 0; hb < 4; ++hb)
#pragma unroll
            for (int kh = 0; kh < 2; ++kh)
                bv[hb][kh] = *(const short8*)(vfp + (hb * 2 + kh) * 512);

        // S^T = Q . K^T : D row = s_loc = sb*16+quad*4+r, col = t_loc = ln15
        floatx4 sacc[4][2];
#pragma unroll
        for (int sb = 0; sb < 4; ++sb)
#pragma unroll
            for (int tg = 0; tg < 2; ++tg) {
                floatx4 z = (floatx4){0.f, 0.f, 0.f, 0.f};
                z = __builtin_amdgcn_mfma_f32_16x16x32_bf16(aq[sb][0], bk[tg][0], z, 0, 0, 0);
                z = __builtin_amdgcn_mfma_f32_16x16x32_bf16(aq[sb][1], bk[tg][1], z, 0, 0, 0);
                sacc[sb][tg] = z;
            }

        // p = exp2(z) (bounded; scale folded into K); mask diag; pack P
        bool diag = (st == dtile);
        int s0 = st * 64;
#pragma unroll
        for (int tg = 0; tg < 2; ++tg) {
            int tgl = base + tg * 16 + ln15;
#pragma unroll
            for (int sb = 0; sb < 4; ++sb) {
                float pv4[4];
#pragma unroll
                for (int r = 0; r < 4; ++r) {
                    float p = __builtin_amdgcn_exp2f(sacc[sb][tg][r]);
                    if (diag) {
                        int sg = s0 + sb * 16 + quad * 4 + r;
                        p = (sg > tgl) ? 0.f : p;
                    }
                    pv4[r] = p;
                }
                ls[tg] += (pv4[0] + pv4[1]) + (pv4[2] + pv4[3]);
                unsigned a01, a23;
                asm("v_cvt_pk_bf16_f32 %0, %1, %2" : "=v"(a01) : "v"(pv4[0]), "v"(pv4[1]));
                asm("v_cvt_pk_bf16_f32 %0, %1, %2" : "=v"(a23) : "v"(pv4[2]), "v"(pv4[3]));
                *(uint2v*)&Ps[tg * 16 + ln15][sb * 16 + quad * 4] = (uint2v){a01, a23};
            }
        }
        // cross-lane LDS RAW: fence is mandatory (round-2..5/9 proven)
        __asm__ volatile("s_waitcnt lgkmcnt(0)" ::: "memory");
        short8 ap[2][2];
#pragma unroll
        for (int tg = 0; tg < 2; ++tg) {
            ap[tg][0] = *(const short8*)&Ps[tg * 16 + ln15][quad * 8];
            ap[tg][1] = *(const short8*)&Ps[tg * 16 + ln15][32 + quad * 8];
        }

        // O += P . V
#pragma unroll
        for (int tg = 0; tg < 2; ++tg)
#pragma unroll
            for (int hb = 0; hb < 4; ++hb) {
                o[tg][hb] = __builtin_amdgcn_mfma_f32_16x16x32_bf16(ap[tg][0], bv[hb][0], o[tg][hb], 0, 0, 0);
                o[tg][hb] = __builtin_amdgcn_mfma_f32_16x16x32_bf16(ap[tg][1], bv[hb][1], o[tg][hb], 0, 0, 0);
            }

        qfp += 8 * 512;
        vfp += 8 * 512;
    }

    // ---- plain-store merge into private chunk slice (b,c) ----
    float* op = Opart + ((size_t)(b * 16 + c) << 12) * HEAD;
    float* lp = lpart + ((size_t)(b * 16 + c) << 12);

#pragma unroll
    for (int tg = 0; tg < 2; ++tg) {
        float v = ls[tg];
        v += __shfl_xor(v, 16, 64);
        v += __shfl_xor(v, 32, 64);
        if (quad == 0)
            lp[base + tg * 16 + ln15] = v;
    }
#pragma unroll
    for (int tg = 0; tg < 2; ++tg)
#pragma unroll
        for (int r = 0; r < 4; ++r) {
            int t = base + tg * 16 + quad * 4 + r;
#pragma unroll
            for (int hb = 0; hb < 4; ++hb)
                op[(size_t)t * HEAD + hb * 16 + ln15] = o[tg][hb][r];
        }
}

// ---------------------------------------------------------------------------
// Kernel 3: out[b,t,h] = sum_c Opart[b,c,t,h] / sum_c lpart[b,c,t]
// chunk c covers s-tiles [4c,4c+3] (s rows 256c..256c+255); contributes
// iff 4c <= t>>6  <=>  c <= t>>8. Exactly matches which waves wrote.
// ---------------------------------------------------------------------------
__global__ __launch_bounds__(256) void attn_div(
    const float* __restrict__ Opart, const float* __restrict__ lpart,
    float* __restrict__ out) {
    int idx = blockIdx.x * 256 + threadIdx.x;   // 0 .. 1048575
    int h = idx & 63;
    int t = (idx >> 6) & 4095;
    int b = idx >> 18;
    int nch = (t >> 8) + 1;
    float os = 0.f, l = 0.f;
    for (int c = 0; c < nch; ++c) {
        size_t s = (size_t)(b * 16 + c) << 12;
        os += Opart[(s + t) * HEAD + h];
        l  += lpart[s + t];
    }
    out[idx] = os / l;
}

extern "C" void kernel_launch(void* const* d_in, const int* in_sizes, int n_in,
                              void* d_out, int out_size, void* d_ws, size_t ws_size,
                              hipStream_t stream) {
    // Size-based input mapping (order-robust; W's and b's keep internal order)
    const int XSZ = 4 * T_SEQ * C_EMB;   // 12582912
    const int WSZ = C_EMB * HEAD;        // 49152
    const int BSZ = HEAD;                // 64
    const float* x = nullptr;
    const float* W[3] = {nullptr, nullptr, nullptr};
    const float* B[3] = {nullptr, nullptr, nullptr};
    int iw = 0, ib = 0;
    for (int i = 0; i < n_in; ++i) {
        if (in_sizes[i] == XSZ) x = (const float*)d_in[i];
        else if (in_sizes[i] == WSZ && iw < 3) W[iw++] = (const float*)d_in[i];
        else if (in_sizes[i] == BSZ && ib < 3) B[ib++] = (const float*)d_in[i];
    }

    short* ws = (short*)d_ws;
    short* Kf = ws;                               // frag-order K bf16   2 MB
    short* Qf = Kf + (size_t)4 * T_SEQ * HEAD;    // frag-order Q bf16   2 MB
    short* Vf = Qf + (size_t)4 * T_SEQ * HEAD;    // frag-order V bf16   2 MB
    short* Wf = Vf + (size_t)4 * HEAD * T_SEQ;    // frag-order W bf16  288 KB
    float* Opart = (float*)(Wf + (size_t)3 * HEAD * C_EMB); // [4][16][4096][64] 64 MB
    float* lpart = Opart + (size_t)64 * T_SEQ * HEAD;       // [4][16][4096] 1 MB

    wt_transpose_kernel<<<96, 256, 0, stream>>>(W[0], W[1], W[2], Wf);
    qkv_mfma<<<512, 512, 0, stream>>>(x, Wf, B[0], B[1], B[2], Kf, Qf, Vf);
    attn_part<<<dim3(128, 16, 4), 64, 0, stream>>>(Kf, Qf, Vf, Opart, lpart);
    attn_div<<<4096, 256, 0, stream>>>(Opart, lpart, (float*)d_out);
}